// Round 7
// baseline (6544.877 us; speedup 1.0000x reference)
//
#include <hip/hip_runtime.h>
#include <hip/hip_bf16.h>

#define BB 8
#define NN 2048
#define KK 20
#define BBNN (BB * NN)

typedef __hip_bfloat16 bf16;
typedef unsigned short u16;

__device__ __forceinline__ float b2f(bf16 v) { return __bfloat162float(v); }

// ---------------------------------------------------------------- sq + transpose (fused)
template<int C>
__global__ __launch_bounds__(256) void sqT_kernel(const float* __restrict__ xin,
                                                  float* __restrict__ sq,
                                                  float* __restrict__ xT) {
    int t = blockIdx.x * 256 + threadIdx.x;
    if (t >= BBNN) return;
    const float* p = xin + (size_t)t * C;
    float s = 0.f;
    for (int c = 0; c < C; ++c) {
        float v = p[c];
        s += v * v;
        xT[(size_t)c * BBNN + t] = v;
    }
    sq[t] = s;
}

// ---------------------------------------------------------------- fast kNN v2
// Block = 1024 threads = 16 waves = 16 queries (one wave per query).
// Phase A: j-tiles of 128 staged once into LDS (xs[C][128], 32 KB for C=64) and
// reused by all 16 waves; lane s computes j = t*128 + {s, 64+s} with the same
// c-ascending fp32 FMA order as the round-5/6 passing kernels -> identical
// neighbor sets. Distances live in per-lane REGISTERS d[32] (r = j>>6).
// Phase B: 20 rounds of lexicographic (d, j) argmin: per-lane cached minimum,
// 6-step shfl_xor wave reduce, winner lane marks its register via unrolled
// compare-select and rescans registers (no LDS in the serial chain).
template<int C>
__global__ __launch_bounds__(1024, 2) void knn_fast_kernel(
        const float* __restrict__ xrows,   // [BBNN][C] row-major (query reads)
        const float* __restrict__ xT,      // [C][BBNN] transposed (neighbor reads)
        const float* __restrict__ sq,
        u16* __restrict__ idx_out) {
    __shared__ float xs[C][128];
    const int blk = blockIdx.x;            // BB * 128
    const int b = blk >> 7;
    const int tile = blk & 127;
    const int w = threadIdx.x >> 6;        // wave id = query within tile
    const int s = threadIdx.x & 63;
    const int i = tile * 16 + w;
    const int bn0 = b * NN;

    // query row -> wave-uniform scalar registers
    const int qbase = __builtin_amdgcn_readfirstlane((bn0 + i) * C);
    float xq[C];
    #pragma unroll
    for (int c = 0; c < C; ++c) xq[c] = xrows[qbase + c];
    const float sqi = sq[bn0 + i];

    float d[32];

    // ---- phase A: 16 tiles of 128 neighbors
    #pragma unroll
    for (int t = 0; t < 16; ++t) {
        const int j0 = t * 128;
        __syncthreads();   // xs safe to overwrite
        for (int e4 = threadIdx.x; e4 < C * 32; e4 += 1024) {
            int c = e4 >> 5;
            int j4 = (e4 & 31) << 2;
            float4 v = *(const float4*)(xT + (size_t)c * BBNN + bn0 + j0 + j4);
            *(float4*)&xs[c][j4] = v;
        }
        __syncthreads();
        float ax = 0.f, ay = 0.f;
        #pragma unroll
        for (int c = 0; c < C; ++c) {
            float q = xq[c];
            ax += q * xs[c][s];
            ay += q * xs[c][64 + s];
        }
        d[2 * t]     = (sqi + sq[bn0 + j0 + s])      - 2.f * ax;
        d[2 * t + 1] = (sqi + sq[bn0 + j0 + 64 + s]) - 2.f * ay;
    }

    // ---- phase B: 20 rounds of lexicographic (dist, j) argmin
    float ld = INFINITY; int lj = 0x7fffffff;
    #pragma unroll
    for (int r = 0; r < 32; ++r) {
        int j = ((r >> 1) << 7) + ((r & 1) << 6) + s;
        if (d[r] < ld) { ld = d[r]; lj = j; }   // ascending j: strict < keeps lowest
    }
    for (int k = 0; k < KK; ++k) {
        float rd = ld; int rj = lj;
        #pragma unroll
        for (int m = 1; m < 64; m <<= 1) {
            float od = __shfl_xor(rd, m);
            int   oj = __shfl_xor(rj, m);
            if (od < rd || (od == rd && oj < rj)) { rd = od; rj = oj; }
        }
        if (s == 0) idx_out[(size_t)(bn0 + i) * KK + k] = (u16)rj;
        if (k + 1 < KK) {
            if (s == (rj & 63)) {            // winner lane: mark + rescan registers
                int rr = rj >> 6;
                ld = INFINITY; lj = 0x7fffffff;
                #pragma unroll
                for (int r = 0; r < 32; ++r) {
                    if (r == rr) d[r] = INFINITY;
                    int j = ((r >> 1) << 7) + ((r & 1) << 6) + s;
                    if (d[r] < ld) { ld = d[r]; lj = j; }
                }
            }
        }
    }
}

// ---------------------------------------------------------------- EdgeConv MLP + max over K
template<int CIN, int COUT, bool BF16OUT>
__global__ __launch_bounds__(COUT) void edgeconv_kernel(
        const float* __restrict__ xin, const u16* __restrict__ knn,
        const float* __restrict__ w1, const float* __restrict__ b1,
        const float* __restrict__ w2, const float* __restrict__ b2,
        void* __restrict__ out) {
    const int bn = blockIdx.x;
    const int b = bn >> 11;
    const int tid = threadIdx.x;   // blockDim == COUT (>= 64, >= CIN)
    __shared__ bf16 w1s[2 * CIN * 64];
    __shared__ bf16 w2s[64 * COUT];
    __shared__ float b1s[64], b2s[COUT], xi[CIN], e[2 * CIN], h1[64];

    for (int p = tid; p < 2 * CIN * 64; p += COUT) w1s[p] = __float2bfloat16(w1[p]);
    for (int p = tid; p < 64 * COUT; p += COUT)    w2s[p] = __float2bfloat16(w2[p]);
    if (tid < 64) b1s[tid] = b1[tid];
    b2s[tid] = b2[tid];
    if (tid < CIN) xi[tid] = xin[(size_t)bn * CIN + tid];
    __syncthreads();

    float accmax = -INFINITY;
    for (int k = 0; k < KK; ++k) {
        int j = knn[bn * KK + k];
        if (j >= NN) j = 0;   // safety clamp
        if (tid < CIN) {
            float xj = xin[((size_t)(b * NN + j)) * CIN + tid];
            e[tid] = xi[tid];
            e[CIN + tid] = xj - xi[tid];
        }
        __syncthreads();
        if (tid < 64) {
            float v = 0.f;
            for (int c = 0; c < 2 * CIN; ++c) v += e[c] * b2f(w1s[c * 64 + tid]);
            h1[tid] = fmaxf(v + b1s[tid], 0.f);
        }
        __syncthreads();
        {
            float v = 0.f;
            for (int c = 0; c < 64; ++c) v += h1[c] * b2f(w2s[c * COUT + tid]);
            accmax = fmaxf(accmax, v + b2s[tid]);
        }
        __syncthreads();
    }
    if (BF16OUT) ((bf16*)out)[(size_t)bn * COUT + tid] = __float2bfloat16(accmax);
    else         ((float*)out)[(size_t)bn * COUT + tid] = accmax;
}

// ---------------------------------------------------------------- global max over N (2-stage)
__global__ __launch_bounds__(128) void gmax1_kernel(const bf16* __restrict__ f2,
                                                    float* __restrict__ pmax) {
    const int b = blockIdx.x >> 4, ch = blockIdx.x & 15, c = threadIdx.x;
    float m = -INFINITY;
    const bf16* base = f2 + ((size_t)(b * NN + ch * 128)) * 128 + c;
    for (int n = 0; n < 128; ++n) m = fmaxf(m, b2f(base[(size_t)n * 128]));
    pmax[blockIdx.x * 128 + c] = m;
}

__global__ __launch_bounds__(128) void gmax2_kernel(const float* __restrict__ pmax,
                                                    float* __restrict__ glob) {
    const int b = blockIdx.x, c = threadIdx.x;
    float m = -INFINITY;
    for (int ch = 0; ch < 16; ++ch) m = fmaxf(m, pmax[(b * 16 + ch) * 128 + c]);
    glob[b * 128 + c] = m;
}

// ---------------------------------------------------------------- K_h, V_h for one head (4 rows/block)
__global__ __launch_bounds__(256) void kvh_kernel(const bf16* __restrict__ f2,
                                                  const float* __restrict__ qkv_w,
                                                  bf16* __restrict__ kk,
                                                  bf16* __restrict__ vv, int h) {
    const int bn0 = blockIdx.x * 4;
    const int tid = threadIdx.x;
    __shared__ float Ws[2][128][32];  // 32 KB: [K|V][c][d] for head h
    __shared__ float f2s[4][128];
    for (int p = tid; p < 2 * 128 * 32; p += 256) {
        int kv = p >> 12, c = (p >> 5) & 127, d = p & 31;
        Ws[kv][c][d] = qkv_w[c * 384 + 128 + kv * 128 + h * 32 + d];
    }
    for (int p = tid; p < 4 * 128; p += 256) {
        int rr = p >> 7, c = p & 127;
        f2s[rr][c] = b2f(f2[(size_t)(bn0 + rr) * 128 + c]);
    }
    __syncthreads();
    const int rr = tid >> 6, u = tid & 63, kv = u >> 5, d = u & 31;
    float acc = 0.f;
    for (int c = 0; c < 128; ++c) acc += f2s[rr][c] * Ws[kv][c][d];
    bf16* dst = kv ? vv : kk;
    dst[(size_t)(bn0 + rr) * 32 + d] = __float2bfloat16(acc);
}

// ---------------------------------------------------------------- attention, one head (exact 2-pass softmax)
__global__ __launch_bounds__(256) void attnh_kernel(const bf16* __restrict__ f2,
                                                    const float* __restrict__ qkv_w,
                                                    const bf16* __restrict__ kk,
                                                    const bf16* __restrict__ vv,
                                                    bf16* __restrict__ atth, int h) {
    const int blk = blockIdx.x;            // B*32 = 256
    const int tile = blk & 31;
    const int b = blk >> 5;
    const int tid = threadIdx.x;
    const int r = tid & 63;
    const int sp = tid >> 6;
    const int i = tile * 64 + r;
    const float scale = 0.17677669529663687f;  // 32^-0.5
    __shared__ float WqS[128 * 32];        // 16 KB
    __shared__ float mred[4][64], lred[4][64];
    __shared__ float accs[4][64][32];      // 32 KB

    for (int p = tid; p < 4096; p += 256) {
        int c = p >> 5, d = p & 31;
        WqS[p] = qkv_w[c * 384 + h * 32 + d];
    }
    __syncthreads();

    float q[32];
    #pragma unroll
    for (int d = 0; d < 32; ++d) q[d] = 0.f;
    const bf16* frow = f2 + (size_t)(b * NN + i) * 128;
    for (int c = 0; c < 128; ++c) {
        float fv = b2f(frow[c]);
        const float* wrow = &WqS[c * 32];
        #pragma unroll
        for (int d = 0; d < 32; ++d) q[d] += fv * wrow[d];
    }

    const bf16* kb = kk + (size_t)b * NN * 32;
    const bf16* vb = vv + (size_t)b * NN * 32;
    const int j0 = sp * 512, j1 = j0 + 512;

    float m = -INFINITY;
    for (int j = j0; j < j1; ++j) {
        const bf16* kr = kb + (size_t)j * 32;
        float dsum = 0.f;
        #pragma unroll
        for (int d = 0; d < 32; ++d) dsum += q[d] * b2f(kr[d]);
        m = fmaxf(m, dsum * scale);
    }
    mred[sp][r] = m;
    __syncthreads();
    m = fmaxf(fmaxf(mred[0][r], mred[1][r]), fmaxf(mred[2][r], mred[3][r]));

    float l = 0.f;
    float a[32];
    #pragma unroll
    for (int d = 0; d < 32; ++d) a[d] = 0.f;
    for (int j = j0; j < j1; ++j) {
        const bf16* kr = kb + (size_t)j * 32;
        float dsum = 0.f;
        #pragma unroll
        for (int d = 0; d < 32; ++d) dsum += q[d] * b2f(kr[d]);
        float p = expf(dsum * scale - m);
        l += p;
        const bf16* vr = vb + (size_t)j * 32;
        #pragma unroll
        for (int d = 0; d < 32; ++d) a[d] += p * b2f(vr[d]);
    }
    lred[sp][r] = l;
    #pragma unroll
    for (int d = 0; d < 32; ++d) accs[sp][r][d] = a[d];
    __syncthreads();

    const int row = tid >> 2;
    const int dbase = (tid & 3) * 8;
    const float denom = lred[0][row] + lred[1][row] + lred[2][row] + lred[3][row];
    bf16* orow = atth + (size_t)(b * NN + tile * 64 + row) * 128 + h * 32;
    #pragma unroll
    for (int uu = 0; uu < 8; ++uu) {
        int d = dbase + uu;
        float v = accs[0][row][d] + accs[1][row][d] + accs[2][row][d] + accs[3][row][d];
        orow[d] = __float2bfloat16(v / denom);
    }
}

// ---------------------------------------------------------------- fused out-proj + concat + refine MLP + log_softmax
__global__ __launch_bounds__(128) void final_kernel(
        const bf16* __restrict__ f2, const float* __restrict__ glob,
        const bf16* __restrict__ atth,
        const float* __restrict__ out_w, const float* __restrict__ out_b,
        const float* __restrict__ r1_w, const float* __restrict__ r1_b,
        const float* __restrict__ r2_w, const float* __restrict__ r2_b,
        const float* __restrict__ r3_w, const float* __restrict__ r3_b,
        float* __restrict__ out) {
    const int bn0 = blockIdx.x * 4;
    const int b = bn0 >> 11;
    const int tid = threadIdx.x;
    __shared__ float attin[4][128], comb[4][384], h1[4][128], h2[4][64];
    __shared__ float logits[4][20], lse[4];

    #pragma unroll
    for (int rr = 0; rr < 4; ++rr) {
        attin[rr][tid]      = b2f(atth[(size_t)(bn0 + rr) * 128 + tid]);
        comb[rr][tid]       = b2f(f2[(size_t)(bn0 + rr) * 128 + tid]);
        comb[rr][128 + tid] = glob[b * 128 + tid];
    }
    __syncthreads();
    {
        float a0 = 0.f, a1 = 0.f, a2 = 0.f, a3 = 0.f;
        for (int c = 0; c < 128; ++c) {
            float wv = out_w[c * 128 + tid];
            a0 += attin[0][c] * wv; a1 += attin[1][c] * wv;
            a2 += attin[2][c] * wv; a3 += attin[3][c] * wv;
        }
        float bb = out_b[tid];
        comb[0][256 + tid] = a0 + bb; comb[1][256 + tid] = a1 + bb;
        comb[2][256 + tid] = a2 + bb; comb[3][256 + tid] = a3 + bb;
    }
    __syncthreads();
    {
        float a0 = 0.f, a1 = 0.f, a2 = 0.f, a3 = 0.f;
        for (int c = 0; c < 384; ++c) {
            float wv = r1_w[c * 128 + tid];
            a0 += comb[0][c] * wv; a1 += comb[1][c] * wv;
            a2 += comb[2][c] * wv; a3 += comb[3][c] * wv;
        }
        float bb = r1_b[tid];
        h1[0][tid] = fmaxf(a0 + bb, 0.f); h1[1][tid] = fmaxf(a1 + bb, 0.f);
        h1[2][tid] = fmaxf(a2 + bb, 0.f); h1[3][tid] = fmaxf(a3 + bb, 0.f);
    }
    __syncthreads();
    if (tid < 64) {
        float a0 = 0.f, a1 = 0.f, a2 = 0.f, a3 = 0.f;
        for (int c = 0; c < 128; ++c) {
            float wv = r2_w[c * 64 + tid];
            a0 += h1[0][c] * wv; a1 += h1[1][c] * wv;
            a2 += h1[2][c] * wv; a3 += h1[3][c] * wv;
        }
        float bb = r2_b[tid];
        h2[0][tid] = fmaxf(a0 + bb, 0.f); h2[1][tid] = fmaxf(a1 + bb, 0.f);
        h2[2][tid] = fmaxf(a2 + bb, 0.f); h2[3][tid] = fmaxf(a3 + bb, 0.f);
    }
    __syncthreads();
    if (tid < 20) {
        float a0 = 0.f, a1 = 0.f, a2 = 0.f, a3 = 0.f;
        for (int c = 0; c < 64; ++c) {
            float wv = r3_w[c * 20 + tid];
            a0 += h2[0][c] * wv; a1 += h2[1][c] * wv;
            a2 += h2[2][c] * wv; a3 += h2[3][c] * wv;
        }
        float bb = r3_b[tid];
        logits[0][tid] = a0 + bb; logits[1][tid] = a1 + bb;
        logits[2][tid] = a2 + bb; logits[3][tid] = a3 + bb;
    }
    __syncthreads();
    if (tid < 4) {
        float m = -INFINITY;
        for (int u = 0; u < 20; ++u) m = fmaxf(m, logits[tid][u]);
        float s = 0.f;
        for (int u = 0; u < 20; ++u) s += expf(logits[tid][u] - m);
        lse[tid] = m + logf(s);
    }
    __syncthreads();
    if (tid < 80) {
        int rr = tid / 20, cls = tid % 20;
        out[(size_t)(bn0 + rr) * 20 + cls] = logits[rr][cls] - lse[rr];
    }
}

// ----------------------------------------------------------------------------
// Workspace layout — NEED = 10,555,392 B (proven to fit):
//   [0,        4 MB)  phase 1-3: f1T fp32 (4 MB, knn2 reads)  -> phase 3+: f2 bf16
//   [4 MB,    10 MB)  shared slot:
//     phase 1-2:  sqb fp32 @4M (64 KB) | f1 fp32 @4M+64K (4 MB) |
//                 knn u16 @8M+64K (640 KB) | xT3 fp32 @~8.69M (192 KB)
//     phase 4:    kk bf16 @4M (1 MB) | vv bf16 @5M (1 MB) | atth bf16 @6M (4 MB)
//   [10 MB, +68 KB)   pmax fp32 | glob fp32
extern "C" void kernel_launch(void* const* d_in, const int* in_sizes, int n_in,
                              void* d_out, int out_size, void* d_ws, size_t ws_size,
                              hipStream_t stream) {
    const float* x      = (const float*)d_in[0];
    const float* ec1_w1 = (const float*)d_in[2];
    const float* ec1_b1 = (const float*)d_in[3];
    const float* ec1_w2 = (const float*)d_in[4];
    const float* ec1_b2 = (const float*)d_in[5];
    const float* ec2_w1 = (const float*)d_in[6];
    const float* ec2_b1 = (const float*)d_in[7];
    const float* ec2_w2 = (const float*)d_in[8];
    const float* ec2_b2 = (const float*)d_in[9];
    const float* qkv_w  = (const float*)d_in[10];
    const float* out_w  = (const float*)d_in[11];
    const float* out_b  = (const float*)d_in[12];
    const float* r1_w   = (const float*)d_in[13];
    const float* r1_b   = (const float*)d_in[14];
    const float* r2_w   = (const float*)d_in[15];
    const float* r2_b   = (const float*)d_in[16];
    const float* r3_w   = (const float*)d_in[17];
    const float* r3_b   = (const float*)d_in[18];
    float* out = (float*)d_out;

    const size_t NEED = 10555392;
    if (ws_size < NEED) return;   // guard: clean numeric fail instead of GPU fault

    char* base = (char*)d_ws;
    const size_t MB = 1024 * 1024;
    bf16*  f2   = (bf16*)(base);                      // phase 3+
    float* f1T  = (float*)(base);                     // phase 1-3 (dead before f2 written)
    float* sqb  = (float*)(base + 4 * MB);
    float* f1   = (float*)(base + 4 * MB + 65536);
    u16*   knn  = (u16*)(base + 8 * MB + 65536);      // 640 KB
    float* xT3  = (float*)(base + 8 * MB + 65536 + 655360);  // 192 KB, ends < 9.3 MB
    bf16*  kk   = (bf16*)(base + 4 * MB);             // phase-4 slot reuse
    bf16*  vv   = (bf16*)(base + 5 * MB);
    bf16*  atth = (bf16*)(base + 6 * MB);
    float* pmax = (float*)(base + 10 * MB);
    float* glob = (float*)(base + 10 * MB + 65536);

    sqT_kernel<3><<<BBNN / 256, 256, 0, stream>>>(x, sqb, xT3);
    knn_fast_kernel<3><<<BB * 128, 1024, 0, stream>>>(x, xT3, sqb, knn);
    edgeconv_kernel<3, 64, false><<<BB * NN, 64, 0, stream>>>(
        x, knn, ec1_w1, ec1_b1, ec1_w2, ec1_b2, f1);

    sqT_kernel<64><<<BBNN / 256, 256, 0, stream>>>(f1, sqb, f1T);
    knn_fast_kernel<64><<<BB * 128, 1024, 0, stream>>>(f1, f1T, sqb, knn);
    edgeconv_kernel<64, 128, true><<<BB * NN, 128, 0, stream>>>(
        f1, knn, ec2_w1, ec2_b1, ec2_w2, ec2_b2, f2);

    gmax1_kernel<<<BB * 16, 128, 0, stream>>>(f2, pmax);
    gmax2_kernel<<<BB, 128, 0, stream>>>(pmax, glob);

    for (int h = 0; h < 4; ++h) {
        kvh_kernel<<<BB * NN / 4, 256, 0, stream>>>(f2, qkv_w, kk, vv, h);
        attnh_kernel<<<BB * 32, 256, 0, stream>>>(f2, qkv_w, kk, vv, atth, h);
    }

    final_kernel<<<BB * NN / 4, 128, 0, stream>>>(
        f2, glob, atth, out_w, out_b, r1_w, r1_b, r2_w, r2_b, r3_w, r3_b, out);
}

// Round 8
// 2770.006 us; speedup vs baseline: 2.3628x; 2.3628x over previous
//
#include <hip/hip_runtime.h>
#include <hip/hip_bf16.h>

#define BB 8
#define NN 2048
#define KK 20
#define BBNN (BB * NN)

typedef __hip_bfloat16 bf16;
typedef unsigned short u16;

__device__ __forceinline__ float b2f(bf16 v) { return __bfloat162float(v); }

// load 8 contiguous bf16 (16B-aligned) -> 8 floats
__device__ __forceinline__ void load_bf16x8(const bf16* p, float* f) {
    uint4 u = *(const uint4*)p;
    f[0] = __uint_as_float(u.x << 16); f[1] = __uint_as_float(u.x & 0xffff0000u);
    f[2] = __uint_as_float(u.y << 16); f[3] = __uint_as_float(u.y & 0xffff0000u);
    f[4] = __uint_as_float(u.z << 16); f[5] = __uint_as_float(u.z & 0xffff0000u);
    f[6] = __uint_as_float(u.w << 16); f[7] = __uint_as_float(u.w & 0xffff0000u);
}

// ---------------------------------------------------------------- sq + transpose (fused)
template<int C>
__global__ __launch_bounds__(256) void sqT_kernel(const float* __restrict__ xin,
                                                  float* __restrict__ sq,
                                                  float* __restrict__ xT) {
    int t = blockIdx.x * 256 + threadIdx.x;
    if (t >= BBNN) return;
    const float* p = xin + (size_t)t * C;
    float s = 0.f;
    for (int c = 0; c < C; ++c) {
        float v = p[c];
        s += v * v;
        xT[(size_t)c * BBNN + t] = v;
    }
    sq[t] = s;
}

// ---------------------------------------------------------------- fast kNN v3 (spill-proof)
// Block = 512 threads = 8 waves = 8 queries (one wave per query).
// Phase A: c-chunks of CH (<=8); query chunk xq[CH] loads are wave-uniform ->
// SGPRs (no VGPR cost); neighbor j-tiles of 256 staged in LDS xs[CH][256] and
// shared by all 8 waves. Dot accumulates in registers d[32] (j = r*64 + s).
// Total VGPRs ~45 -> no scratch spill (round-7 lesson: 11.6 GB spill traffic).
// Phase B: 20 rounds of lexicographic (d,j) argmin: per-lane cached min,
// 6-step shfl_xor reduce, winner lane rescans its registers (no LDS).
template<int C, int CH>
__global__ __launch_bounds__(512, 4) void knn_fast_kernel(
        const float* __restrict__ xrows,   // [BBNN][C] row-major (query reads)
        const float* __restrict__ xT,      // [C][BBNN] transposed (neighbor reads)
        const float* __restrict__ sq,
        u16* __restrict__ idx_out) {
    __shared__ float xs[CH][256];
    const int blk = blockIdx.x;            // BB * 256
    const int b = blk >> 8;
    const int tile = blk & 255;
    const int w = threadIdx.x >> 6;        // wave id = query within tile
    const int s = threadIdx.x & 63;
    const int i = tile * 8 + w;
    const int bn0 = b * NN;
    constexpr int NCH = C / CH;            // 1 for C=3, 8 for C=64

    float d[32];
    #pragma unroll
    for (int r = 0; r < 32; ++r) d[r] = 0.f;

    const int qbase = (bn0 + i) * C;       // wave-uniform
    for (int ch = 0; ch < NCH; ++ch) {
        float xq[CH];
        #pragma unroll
        for (int cc = 0; cc < CH; ++cc) xq[cc] = xrows[qbase + ch * CH + cc];
        #pragma unroll 1
        for (int t = 0; t < 8; ++t) {
            __syncthreads();
            for (int p = threadIdx.x; p < CH * 256; p += 512) {
                int c = p >> 8, j = p & 255;
                xs[c][j] = xT[(size_t)(ch * CH + c) * BBNN + bn0 + t * 256 + j];
            }
            __syncthreads();
            float a0 = 0.f, a1 = 0.f, a2 = 0.f, a3 = 0.f;
            #pragma unroll
            for (int cc = 0; cc < CH; ++cc) {
                float q = xq[cc];
                a0 += q * xs[cc][s];
                a1 += q * xs[cc][64 + s];
                a2 += q * xs[cc][128 + s];
                a3 += q * xs[cc][192 + s];
            }
            d[t * 4 + 0] += a0; d[t * 4 + 1] += a1;
            d[t * 4 + 2] += a2; d[t * 4 + 3] += a3;
        }
    }
    const float sqi = sq[bn0 + i];
    #pragma unroll
    for (int r = 0; r < 32; ++r)
        d[r] = (sqi + sq[bn0 + r * 64 + s]) - 2.f * d[r];

    // ---- phase B: 20 rounds of lexicographic (dist, j) argmin
    float ld = INFINITY; int lj = 0x7fffffff;
    #pragma unroll
    for (int r = 0; r < 32; ++r) {
        int j = r * 64 + s;
        if (d[r] < ld) { ld = d[r]; lj = j; }   // ascending j: strict < keeps lowest
    }
    for (int k = 0; k < KK; ++k) {
        float rd = ld; int rj = lj;
        #pragma unroll
        for (int m = 1; m < 64; m <<= 1) {
            float od = __shfl_xor(rd, m);
            int   oj = __shfl_xor(rj, m);
            if (od < rd || (od == rd && oj < rj)) { rd = od; rj = oj; }
        }
        if (s == 0) idx_out[(size_t)(bn0 + i) * KK + k] = (u16)rj;
        if (k + 1 < KK) {
            if (s == (rj & 63)) {            // winner lane: mark + rescan registers
                int rr = rj >> 6;
                ld = INFINITY; lj = 0x7fffffff;
                #pragma unroll
                for (int r = 0; r < 32; ++r) {
                    if (r == rr) d[r] = INFINITY;
                    int j = r * 64 + s;
                    if (d[r] < ld) { ld = d[r]; lj = j; }
                }
            }
        }
    }
}

// ---------------------------------------------------------------- EdgeConv v2: parallel over (k, h)
// One block per point, 256 threads, 4 barriers total (was 60).
// base1[h] = b1[h] + sum_c xi[c]*w1[c][h] is k-invariant (xi half of the edge
// feature) -> halves layer-1 MACs; ediff holds only (xj - xi).
// Layer 2: k-split partial max (SPLIT=256/COUT), then reduce.
template<int CIN, int COUT, bool BF16OUT>
__global__ __launch_bounds__(256) void edgeconv_kernel(
        const float* __restrict__ xin, const u16* __restrict__ knn,
        const float* __restrict__ w1, const float* __restrict__ b1,
        const float* __restrict__ w2, const float* __restrict__ b2,
        void* __restrict__ out) {
    const int bn = blockIdx.x;
    const int b = bn >> 11;
    const int tid = threadIdx.x;
    constexpr int SPLIT = 256 / COUT;      // 2 for COUT=128, 4 for COUT=64
    constexpr int KPS = KK / SPLIT;        // 10 / 5
    __shared__ bf16 w1s[2 * CIN * 64];
    __shared__ bf16 w2s[64 * COUT];
    __shared__ float b1s[64], xi_s[CIN], base1[64];
    __shared__ float ediff[KK][CIN];
    __shared__ float h1s[KK][64];
    __shared__ float pm[SPLIT][COUT];
    __shared__ int js[KK];

    // phase 0: stage weights + xi + neighbor indices
    for (int p = tid; p < 2 * CIN * 64; p += 256) w1s[p] = __float2bfloat16(w1[p]);
    for (int p = tid; p < 64 * COUT; p += 256)    w2s[p] = __float2bfloat16(w2[p]);
    if (tid < 64) b1s[tid] = b1[tid];
    if (tid < CIN) xi_s[tid] = xin[(size_t)bn * CIN + tid];
    if (tid >= 64 && tid < 64 + KK) {
        int j = knn[bn * KK + (tid - 64)];
        js[tid - 64] = (j < NN) ? j : 0;
    }
    __syncthreads();

    // phase 1: ediff[k][c] = xj[c] - xi[c]; base1[h]
    for (int p = tid; p < KK * CIN; p += 256) {
        int k = p / CIN, c = p % CIN;
        ediff[k][c] = xin[((size_t)(b * NN + js[k])) * CIN + c] - xi_s[c];
    }
    if (tid < 64) {
        float a = b1s[tid];
        for (int c = 0; c < CIN; ++c) a += xi_s[c] * b2f(w1s[c * 64 + tid]);
        base1[tid] = a;
    }
    __syncthreads();

    // phase 2: h1[k][h] = relu(base1[h] + ediff[k] . w1[CIN: , h])
    for (int p = tid; p < KK * 64; p += 256) {
        int k = p >> 6, h = p & 63;
        float a = base1[h];
        for (int c = 0; c < CIN; ++c) a += ediff[k][c] * b2f(w1s[(CIN + c) * 64 + h]);
        h1s[k][h] = fmaxf(a, 0.f);
    }
    __syncthreads();

    // phase 3: layer2 + k-split max
    {
        int o = tid % COUT, sp = tid / COUT;
        float mx = -INFINITY;
        for (int kk2 = 0; kk2 < KPS; ++kk2) {
            int k = sp * KPS + kk2;
            float a = 0.f;
            for (int c = 0; c < 64; ++c) a += h1s[k][c] * b2f(w2s[c * COUT + o]);
            mx = fmaxf(mx, a);
        }
        pm[sp][o] = mx;
    }
    __syncthreads();
    if (tid < COUT) {
        float mx = pm[0][tid];
        #pragma unroll
        for (int s2 = 1; s2 < SPLIT; ++s2) mx = fmaxf(mx, pm[s2][tid]);
        mx += b2[tid];                     // max_k(v)+b == max_k(v+b)
        if (BF16OUT) ((bf16*)out)[(size_t)bn * COUT + tid] = __float2bfloat16(mx);
        else         ((float*)out)[(size_t)bn * COUT + tid] = mx;
    }
}

// ---------------------------------------------------------------- global max over N (2-stage)
__global__ __launch_bounds__(128) void gmax1_kernel(const bf16* __restrict__ f2,
                                                    float* __restrict__ pmax) {
    const int b = blockIdx.x >> 4, ch = blockIdx.x & 15, c = threadIdx.x;
    float m = -INFINITY;
    const bf16* base = f2 + ((size_t)(b * NN + ch * 128)) * 128 + c;
    for (int n = 0; n < 128; ++n) m = fmaxf(m, b2f(base[(size_t)n * 128]));
    pmax[blockIdx.x * 128 + c] = m;
}

__global__ __launch_bounds__(128) void gmax2_kernel(const float* __restrict__ pmax,
                                                    float* __restrict__ glob) {
    const int b = blockIdx.x, c = threadIdx.x;
    float m = -INFINITY;
    for (int ch = 0; ch < 16; ++ch) m = fmaxf(m, pmax[(b * 16 + ch) * 128 + c]);
    glob[b * 128 + c] = m;
}

// ---------------------------------------------------------------- K_h, V_h for one head (4 rows/block)
__global__ __launch_bounds__(256) void kvh_kernel(const bf16* __restrict__ f2,
                                                  const float* __restrict__ qkv_w,
                                                  bf16* __restrict__ kk,
                                                  bf16* __restrict__ vv, int h) {
    const int bn0 = blockIdx.x * 4;
    const int tid = threadIdx.x;
    __shared__ float Ws[2][128][32];  // 32 KB
    __shared__ float f2s[4][128];
    for (int p = tid; p < 2 * 128 * 32; p += 256) {
        int kv = p >> 12, c = (p >> 5) & 127, d = p & 31;
        Ws[kv][c][d] = qkv_w[c * 384 + 128 + kv * 128 + h * 32 + d];
    }
    for (int p = tid; p < 4 * 128; p += 256) {
        int rr = p >> 7, c = p & 127;
        f2s[rr][c] = b2f(f2[(size_t)(bn0 + rr) * 128 + c]);
    }
    __syncthreads();
    const int rr = tid >> 6, u = tid & 63, kv = u >> 5, d = u & 31;
    float acc = 0.f;
    for (int c = 0; c < 128; ++c) acc += f2s[rr][c] * Ws[kv][c][d];
    bf16* dst = kv ? vv : kk;
    dst[(size_t)(bn0 + rr) * 32 + d] = __float2bfloat16(acc);
}

// ---------------------------------------------------------------- attention, one head (exact 2-pass softmax)
__global__ __launch_bounds__(256) void attnh_kernel(const bf16* __restrict__ f2,
                                                    const float* __restrict__ qkv_w,
                                                    const bf16* __restrict__ kk,
                                                    const bf16* __restrict__ vv,
                                                    bf16* __restrict__ atth, int h) {
    const int blk = blockIdx.x;            // B*32 = 256
    const int tile = blk & 31;
    const int b = blk >> 5;
    const int tid = threadIdx.x;
    const int r = tid & 63;
    const int sp = tid >> 6;
    const int i = tile * 64 + r;
    const float scale = 0.17677669529663687f;  // 32^-0.5
    __shared__ float WqS[128 * 32];        // 16 KB
    __shared__ float mred[4][64], lred[4][64];
    __shared__ float accs[4][64][32];      // 32 KB

    for (int p = tid; p < 4096; p += 256) {
        int c = p >> 5, d = p & 31;
        WqS[p] = qkv_w[c * 384 + h * 32 + d];
    }
    __syncthreads();

    // q = f2_row @ Wq_h  (vectorized bf16x8 loads; f2 is known-bf16 data)
    float q[32];
    #pragma unroll
    for (int d = 0; d < 32; ++d) q[d] = 0.f;
    const bf16* frow = f2 + (size_t)(b * NN + i) * 128;
    for (int cc = 0; cc < 16; ++cc) {
        float fv[8];
        load_bf16x8(frow + cc * 8, fv);
        #pragma unroll
        for (int u2 = 0; u2 < 8; ++u2) {
            const float* wrow = &WqS[(cc * 8 + u2) * 32];
            #pragma unroll
            for (int d = 0; d < 32; ++d) q[d] += fv[u2] * wrow[d];
        }
    }

    const bf16* kb = kk + (size_t)b * NN * 32;
    const bf16* vb = vv + (size_t)b * NN * 32;
    const int j0 = sp * 512, j1 = j0 + 512;

    float m = -INFINITY;
    for (int j = j0; j < j1; ++j) {
        const bf16* kr = kb + (size_t)j * 32;   // wave-uniform row
        float dsum = 0.f;
        #pragma unroll
        for (int d = 0; d < 32; ++d) dsum += q[d] * b2f(kr[d]);
        m = fmaxf(m, dsum * scale);
    }
    mred[sp][r] = m;
    __syncthreads();
    m = fmaxf(fmaxf(mred[0][r], mred[1][r]), fmaxf(mred[2][r], mred[3][r]));

    float l = 0.f;
    float a[32];
    #pragma unroll
    for (int d = 0; d < 32; ++d) a[d] = 0.f;
    for (int j = j0; j < j1; ++j) {
        const bf16* kr = kb + (size_t)j * 32;
        float dsum = 0.f;
        #pragma unroll
        for (int d = 0; d < 32; ++d) dsum += q[d] * b2f(kr[d]);
        float p = expf(dsum * scale - m);
        l += p;
        const bf16* vr = vb + (size_t)j * 32;
        #pragma unroll
        for (int d = 0; d < 32; ++d) a[d] += p * b2f(vr[d]);
    }
    lred[sp][r] = l;
    #pragma unroll
    for (int d = 0; d < 32; ++d) accs[sp][r][d] = a[d];
    __syncthreads();

    const int row = tid >> 2;
    const int dbase = (tid & 3) * 8;
    const float denom = lred[0][row] + lred[1][row] + lred[2][row] + lred[3][row];
    bf16* orow = atth + (size_t)(b * NN + tile * 64 + row) * 128 + h * 32;
    #pragma unroll
    for (int uu = 0; uu < 8; ++uu) {
        int d = dbase + uu;
        float v = accs[0][row][d] + accs[1][row][d] + accs[2][row][d] + accs[3][row][d];
        orow[d] = __float2bfloat16(v / denom);
    }
}

// ---------------------------------------------------------------- fused out-proj + concat + refine MLP + log_softmax
__global__ __launch_bounds__(128) void final_kernel(
        const bf16* __restrict__ f2, const float* __restrict__ glob,
        const bf16* __restrict__ atth,
        const float* __restrict__ out_w, const float* __restrict__ out_b,
        const float* __restrict__ r1_w, const float* __restrict__ r1_b,
        const float* __restrict__ r2_w, const float* __restrict__ r2_b,
        const float* __restrict__ r3_w, const float* __restrict__ r3_b,
        float* __restrict__ out) {
    const int bn0 = blockIdx.x * 4;
    const int b = bn0 >> 11;
    const int tid = threadIdx.x;
    __shared__ float attin[4][128], comb[4][384], h1[4][128], h2[4][64];
    __shared__ float logits[4][20], lse[4];

    #pragma unroll
    for (int rr = 0; rr < 4; ++rr) {
        attin[rr][tid]      = b2f(atth[(size_t)(bn0 + rr) * 128 + tid]);
        comb[rr][tid]       = b2f(f2[(size_t)(bn0 + rr) * 128 + tid]);
        comb[rr][128 + tid] = glob[b * 128 + tid];
    }
    __syncthreads();
    {
        float a0 = 0.f, a1 = 0.f, a2 = 0.f, a3 = 0.f;
        for (int c = 0; c < 128; ++c) {
            float wv = out_w[c * 128 + tid];
            a0 += attin[0][c] * wv; a1 += attin[1][c] * wv;
            a2 += attin[2][c] * wv; a3 += attin[3][c] * wv;
        }
        float bb = out_b[tid];
        comb[0][256 + tid] = a0 + bb; comb[1][256 + tid] = a1 + bb;
        comb[2][256 + tid] = a2 + bb; comb[3][256 + tid] = a3 + bb;
    }
    __syncthreads();
    {
        float a0 = 0.f, a1 = 0.f, a2 = 0.f, a3 = 0.f;
        for (int c = 0; c < 384; ++c) {
            float wv = r1_w[c * 128 + tid];
            a0 += comb[0][c] * wv; a1 += comb[1][c] * wv;
            a2 += comb[2][c] * wv; a3 += comb[3][c] * wv;
        }
        float bb = r1_b[tid];
        h1[0][tid] = fmaxf(a0 + bb, 0.f); h1[1][tid] = fmaxf(a1 + bb, 0.f);
        h1[2][tid] = fmaxf(a2 + bb, 0.f); h1[3][tid] = fmaxf(a3 + bb, 0.f);
    }
    __syncthreads();
    if (tid < 64) {
        float a0 = 0.f, a1 = 0.f, a2 = 0.f, a3 = 0.f;
        for (int c = 0; c < 128; ++c) {
            float wv = r2_w[c * 64 + tid];
            a0 += h1[0][c] * wv; a1 += h1[1][c] * wv;
            a2 += h1[2][c] * wv; a3 += h1[3][c] * wv;
        }
        float bb = r2_b[tid];
        h2[0][tid] = fmaxf(a0 + bb, 0.f); h2[1][tid] = fmaxf(a1 + bb, 0.f);
        h2[2][tid] = fmaxf(a2 + bb, 0.f); h2[3][tid] = fmaxf(a3 + bb, 0.f);
    }
    __syncthreads();
    if (tid < 20) {
        float a0 = 0.f, a1 = 0.f, a2 = 0.f, a3 = 0.f;
        for (int c = 0; c < 64; ++c) {
            float wv = r3_w[c * 20 + tid];
            a0 += h2[0][c] * wv; a1 += h2[1][c] * wv;
            a2 += h2[2][c] * wv; a3 += h2[3][c] * wv;
        }
        float bb = r3_b[tid];
        logits[0][tid] = a0 + bb; logits[1][tid] = a1 + bb;
        logits[2][tid] = a2 + bb; logits[3][tid] = a3 + bb;
    }
    __syncthreads();
    if (tid < 4) {
        float m = -INFINITY;
        for (int u = 0; u < 20; ++u) m = fmaxf(m, logits[tid][u]);
        float s = 0.f;
        for (int u = 0; u < 20; ++u) s += expf(logits[tid][u] - m);
        lse[tid] = m + logf(s);
    }
    __syncthreads();
    if (tid < 80) {
        int rr = tid / 20, cls = tid % 20;
        out[(size_t)(bn0 + rr) * 20 + cls] = logits[rr][cls] - lse[rr];
    }
}

// ----------------------------------------------------------------------------
// Workspace layout — NEED = 10,555,392 B (proven to fit):
//   [0,        4 MB)  phase 1-3: f1T fp32 (knn2 reads)  -> phase 3+: f2 bf16
//   [4 MB,    10 MB)  shared slot:
//     phase 1-2:  sqb fp32 @4M (64 KB) | f1 fp32 @4M+64K (4 MB) |
//                 knn u16 @8M+64K (640 KB) | xT3 fp32 @~8.69M (192 KB)
//     phase 4:    kk bf16 @4M (1 MB) | vv bf16 @5M (1 MB) | atth bf16 @6M (4 MB)
//   [10 MB, +68 KB)   pmax fp32 | glob fp32
extern "C" void kernel_launch(void* const* d_in, const int* in_sizes, int n_in,
                              void* d_out, int out_size, void* d_ws, size_t ws_size,
                              hipStream_t stream) {
    const float* x      = (const float*)d_in[0];
    const float* ec1_w1 = (const float*)d_in[2];
    const float* ec1_b1 = (const float*)d_in[3];
    const float* ec1_w2 = (const float*)d_in[4];
    const float* ec1_b2 = (const float*)d_in[5];
    const float* ec2_w1 = (const float*)d_in[6];
    const float* ec2_b1 = (const float*)d_in[7];
    const float* ec2_w2 = (const float*)d_in[8];
    const float* ec2_b2 = (const float*)d_in[9];
    const float* qkv_w  = (const float*)d_in[10];
    const float* out_w  = (const float*)d_in[11];
    const float* out_b  = (const float*)d_in[12];
    const float* r1_w   = (const float*)d_in[13];
    const float* r1_b   = (const float*)d_in[14];
    const float* r2_w   = (const float*)d_in[15];
    const float* r2_b   = (const float*)d_in[16];
    const float* r3_w   = (const float*)d_in[17];
    const float* r3_b   = (const float*)d_in[18];
    float* out = (float*)d_out;

    const size_t NEED = 10555392;
    if (ws_size < NEED) return;   // guard: clean numeric fail instead of GPU fault

    char* base = (char*)d_ws;
    const size_t MB = 1024 * 1024;
    bf16*  f2   = (bf16*)(base);                      // phase 3+
    float* f1T  = (float*)(base);                     // phase 1-3 (dead before f2 written)
    float* sqb  = (float*)(base + 4 * MB);
    float* f1   = (float*)(base + 4 * MB + 65536);
    u16*   knn  = (u16*)(base + 8 * MB + 65536);      // 640 KB
    float* xT3  = (float*)(base + 8 * MB + 65536 + 655360);  // 192 KB
    bf16*  kk   = (bf16*)(base + 4 * MB);             // phase-4 slot reuse
    bf16*  vv   = (bf16*)(base + 5 * MB);
    bf16*  atth = (bf16*)(base + 6 * MB);
    float* pmax = (float*)(base + 10 * MB);
    float* glob = (float*)(base + 10 * MB + 65536);

    sqT_kernel<3><<<BBNN / 256, 256, 0, stream>>>(x, sqb, xT3);
    knn_fast_kernel<3, 3><<<BB * 256, 512, 0, stream>>>(x, xT3, sqb, knn);
    edgeconv_kernel<3, 64, false><<<BB * NN, 256, 0, stream>>>(
        x, knn, ec1_w1, ec1_b1, ec1_w2, ec1_b2, f1);

    sqT_kernel<64><<<BBNN / 256, 256, 0, stream>>>(f1, sqb, f1T);
    knn_fast_kernel<64, 8><<<BB * 256, 512, 0, stream>>>(f1, f1T, sqb, knn);
    edgeconv_kernel<64, 128, true><<<BB * NN, 256, 0, stream>>>(
        f1, knn, ec2_w1, ec2_b1, ec2_w2, ec2_b2, f2);

    gmax1_kernel<<<BB * 16, 128, 0, stream>>>(f2, pmax);
    gmax2_kernel<<<BB, 128, 0, stream>>>(pmax, glob);

    for (int h = 0; h < 4; ++h) {
        kvh_kernel<<<BB * NN / 4, 256, 0, stream>>>(f2, qkv_w, kk, vv, h);
        attnh_kernel<<<BB * 32, 256, 0, stream>>>(f2, qkv_w, kk, vv, atth, h);
    }

    final_kernel<<<BB * NN / 4, 128, 0, stream>>>(
        f2, glob, atth, out_w, out_b, r1_w, r1_b, r2_w, r2_b, r3_w, r3_b, out);
}

// Round 9
// 2237.603 us; speedup vs baseline: 2.9249x; 1.2379x over previous
//
#include <hip/hip_runtime.h>
#include <hip/hip_bf16.h>

#define BB 8
#define NN 2048
#define KK 20
#define BBNN (BB * NN)

typedef __hip_bfloat16 bf16;
typedef unsigned short u16;

__device__ __forceinline__ float b2f(bf16 v) { return __bfloat162float(v); }

// load 8 contiguous bf16 (16B-aligned) -> 8 floats
__device__ __forceinline__ void load_bf16x8(const bf16* p, float* f) {
    uint4 u = *(const uint4*)p;
    f[0] = __uint_as_float(u.x << 16); f[1] = __uint_as_float(u.x & 0xffff0000u);
    f[2] = __uint_as_float(u.y << 16); f[3] = __uint_as_float(u.y & 0xffff0000u);
    f[4] = __uint_as_float(u.z << 16); f[5] = __uint_as_float(u.z & 0xffff0000u);
    f[6] = __uint_as_float(u.w << 16); f[7] = __uint_as_float(u.w & 0xffff0000u);
}

// ---------------------------------------------------------------- sq + transpose (fused)
template<int C>
__global__ __launch_bounds__(256) void sqT_kernel(const float* __restrict__ xin,
                                                  float* __restrict__ sq,
                                                  float* __restrict__ xT) {
    int t = blockIdx.x * 256 + threadIdx.x;
    if (t >= BBNN) return;
    const float* p = xin + (size_t)t * C;
    float s = 0.f;
    for (int c = 0; c < C; ++c) {
        float v = p[c];
        s += v * v;
        xT[(size_t)c * BBNN + t] = v;
    }
    sq[t] = s;
}

// ---------------------------------------------------------------- fast kNN v3 (spill-proof)
template<int C, int CH>
__global__ __launch_bounds__(512, 4) void knn_fast_kernel(
        const float* __restrict__ xrows,   // [BBNN][C] row-major (query reads)
        const float* __restrict__ xT,      // [C][BBNN] transposed (neighbor reads)
        const float* __restrict__ sq,
        u16* __restrict__ idx_out) {
    __shared__ float xs[CH][256];
    const int blk = blockIdx.x;            // BB * 256
    const int b = blk >> 8;
    const int tile = blk & 255;
    const int w = threadIdx.x >> 6;
    const int s = threadIdx.x & 63;
    const int i = tile * 8 + w;
    const int bn0 = b * NN;
    constexpr int NCH = C / CH;

    float d[32];
    #pragma unroll
    for (int r = 0; r < 32; ++r) d[r] = 0.f;

    const int qbase = (bn0 + i) * C;
    for (int ch = 0; ch < NCH; ++ch) {
        float xq[CH];
        #pragma unroll
        for (int cc = 0; cc < CH; ++cc) xq[cc] = xrows[qbase + ch * CH + cc];
        #pragma unroll 1
        for (int t = 0; t < 8; ++t) {
            __syncthreads();
            for (int p = threadIdx.x; p < CH * 256; p += 512) {
                int c = p >> 8, j = p & 255;
                xs[c][j] = xT[(size_t)(ch * CH + c) * BBNN + bn0 + t * 256 + j];
            }
            __syncthreads();
            float a0 = 0.f, a1 = 0.f, a2 = 0.f, a3 = 0.f;
            #pragma unroll
            for (int cc = 0; cc < CH; ++cc) {
                float q = xq[cc];
                a0 += q * xs[cc][s];
                a1 += q * xs[cc][64 + s];
                a2 += q * xs[cc][128 + s];
                a3 += q * xs[cc][192 + s];
            }
            d[t * 4 + 0] += a0; d[t * 4 + 1] += a1;
            d[t * 4 + 2] += a2; d[t * 4 + 3] += a3;
        }
    }
    const float sqi = sq[bn0 + i];
    #pragma unroll
    for (int r = 0; r < 32; ++r)
        d[r] = (sqi + sq[bn0 + r * 64 + s]) - 2.f * d[r];

    float ld = INFINITY; int lj = 0x7fffffff;
    #pragma unroll
    for (int r = 0; r < 32; ++r) {
        int j = r * 64 + s;
        if (d[r] < ld) { ld = d[r]; lj = j; }
    }
    for (int k = 0; k < KK; ++k) {
        float rd = ld; int rj = lj;
        #pragma unroll
        for (int m = 1; m < 64; m <<= 1) {
            float od = __shfl_xor(rd, m);
            int   oj = __shfl_xor(rj, m);
            if (od < rd || (od == rd && oj < rj)) { rd = od; rj = oj; }
        }
        if (s == 0) idx_out[(size_t)(bn0 + i) * KK + k] = (u16)rj;
        if (k + 1 < KK) {
            if (s == (rj & 63)) {
                int rr = rj >> 6;
                ld = INFINITY; lj = 0x7fffffff;
                #pragma unroll
                for (int r = 0; r < 32; ++r) {
                    if (r == rr) d[r] = INFINITY;
                    int j = r * 64 + s;
                    if (d[r] < ld) { ld = d[r]; lj = j; }
                }
            }
        }
    }
}

// ---------------------------------------------------------------- EdgeConv v2: parallel over (k, h)
template<int CIN, int COUT, bool BF16OUT>
__global__ __launch_bounds__(256) void edgeconv_kernel(
        const float* __restrict__ xin, const u16* __restrict__ knn,
        const float* __restrict__ w1, const float* __restrict__ b1,
        const float* __restrict__ w2, const float* __restrict__ b2,
        void* __restrict__ out) {
    const int bn = blockIdx.x;
    const int b = bn >> 11;
    const int tid = threadIdx.x;
    constexpr int SPLIT = 256 / COUT;
    constexpr int KPS = KK / SPLIT;
    __shared__ bf16 w1s[2 * CIN * 64];
    __shared__ bf16 w2s[64 * COUT];
    __shared__ float b1s[64], xi_s[CIN], base1[64];
    __shared__ float ediff[KK][CIN];
    __shared__ float h1s[KK][64];
    __shared__ float pm[SPLIT][COUT];
    __shared__ int js[KK];

    for (int p = tid; p < 2 * CIN * 64; p += 256) w1s[p] = __float2bfloat16(w1[p]);
    for (int p = tid; p < 64 * COUT; p += 256)    w2s[p] = __float2bfloat16(w2[p]);
    if (tid < 64) b1s[tid] = b1[tid];
    if (tid < CIN) xi_s[tid] = xin[(size_t)bn * CIN + tid];
    if (tid >= 64 && tid < 64 + KK) {
        int j = knn[bn * KK + (tid - 64)];
        js[tid - 64] = (j < NN) ? j : 0;
    }
    __syncthreads();

    for (int p = tid; p < KK * CIN; p += 256) {
        int k = p / CIN, c = p % CIN;
        ediff[k][c] = xin[((size_t)(b * NN + js[k])) * CIN + c] - xi_s[c];
    }
    if (tid < 64) {
        float a = b1s[tid];
        for (int c = 0; c < CIN; ++c) a += xi_s[c] * b2f(w1s[c * 64 + tid]);
        base1[tid] = a;
    }
    __syncthreads();

    for (int p = tid; p < KK * 64; p += 256) {
        int k = p >> 6, h = p & 63;
        float a = base1[h];
        for (int c = 0; c < CIN; ++c) a += ediff[k][c] * b2f(w1s[(CIN + c) * 64 + h]);
        h1s[k][h] = fmaxf(a, 0.f);
    }
    __syncthreads();

    {
        int o = tid % COUT, sp = tid / COUT;
        float mx = -INFINITY;
        for (int kk2 = 0; kk2 < KPS; ++kk2) {
            int k = sp * KPS + kk2;
            float a = 0.f;
            for (int c = 0; c < 64; ++c) a += h1s[k][c] * b2f(w2s[c * COUT + o]);
            mx = fmaxf(mx, a);
        }
        pm[sp][o] = mx;
    }
    __syncthreads();
    if (tid < COUT) {
        float mx = pm[0][tid];
        #pragma unroll
        for (int s2 = 1; s2 < SPLIT; ++s2) mx = fmaxf(mx, pm[s2][tid]);
        mx += b2[tid];
        if (BF16OUT) ((bf16*)out)[(size_t)bn * COUT + tid] = __float2bfloat16(mx);
        else         ((float*)out)[(size_t)bn * COUT + tid] = mx;
    }
}

// ---------------------------------------------------------------- global max over N (2-stage)
__global__ __launch_bounds__(128) void gmax1_kernel(const bf16* __restrict__ f2,
                                                    float* __restrict__ pmax) {
    const int b = blockIdx.x >> 4, ch = blockIdx.x & 15, c = threadIdx.x;
    float m = -INFINITY;
    const bf16* base = f2 + ((size_t)(b * NN + ch * 128)) * 128 + c;
    for (int n = 0; n < 128; ++n) m = fmaxf(m, b2f(base[(size_t)n * 128]));
    pmax[blockIdx.x * 128 + c] = m;
}

__global__ __launch_bounds__(128) void gmax2_kernel(const float* __restrict__ pmax,
                                                    float* __restrict__ glob) {
    const int b = blockIdx.x, c = threadIdx.x;
    float m = -INFINITY;
    for (int ch = 0; ch < 16; ++ch) m = fmaxf(m, pmax[(b * 16 + ch) * 128 + c]);
    glob[b * 128 + c] = m;
}

// ---------------------------------------------------------------- K_h, V_h for one head (4 rows/block)
// ostride: row stride of kk/vv output (32 = per-head buffer, 128 = all-heads)
__global__ __launch_bounds__(256) void kvh_kernel(const bf16* __restrict__ f2,
                                                  const float* __restrict__ qkv_w,
                                                  bf16* __restrict__ kk,
                                                  bf16* __restrict__ vv,
                                                  int h, int ostride) {
    const int bn0 = blockIdx.x * 4;
    const int tid = threadIdx.x;
    __shared__ float Ws[2][128][32];
    __shared__ float f2s[4][128];
    for (int p = tid; p < 2 * 128 * 32; p += 256) {
        int kv = p >> 12, c = (p >> 5) & 127, d = p & 31;
        Ws[kv][c][d] = qkv_w[c * 384 + 128 + kv * 128 + h * 32 + d];
    }
    for (int p = tid; p < 4 * 128; p += 256) {
        int rr = p >> 7, c = p & 127;
        f2s[rr][c] = b2f(f2[(size_t)(bn0 + rr) * 128 + c]);
    }
    __syncthreads();
    const int rr = tid >> 6, u = tid & 63, kv = u >> 5, d = u & 31;
    float acc = 0.f;
    for (int c = 0; c < 128; ++c) acc += f2s[rr][c] * Ws[kv][c][d];
    bf16* dst = kv ? vv : kk;
    dst[(size_t)(bn0 + rr) * ostride + d] = __float2bfloat16(acc);
}

// ---------------------------------------------------------------- attention (exact 2-pass softmax)
// h_in >= 0: single head (grid = B*32, per-head K/V with kstride=32).
// h_in < 0:  all heads in grid (grid = 4*B*32, all-heads K/V with kstride=128,
//            head offset h*32 added inside).
__global__ __launch_bounds__(256) void attnh_kernel(const bf16* __restrict__ f2,
                                                    const float* __restrict__ qkv_w,
                                                    const bf16* __restrict__ kk,
                                                    const bf16* __restrict__ vv,
                                                    bf16* __restrict__ atth,
                                                    int h_in, int kstride) {
    int blk = blockIdx.x;
    int h;
    if (h_in < 0) { h = blk >> 8; blk &= 255; } else { h = h_in; }
    const int tile = blk & 31;
    const int b = blk >> 5;
    const int tid = threadIdx.x;
    const int r = tid & 63;
    const int sp = tid >> 6;
    const int i = tile * 64 + r;
    const float scale = 0.17677669529663687f;  // 32^-0.5
    __shared__ float WqS[128 * 32];        // 16 KB
    __shared__ float mred[4][64], lred[4][64];
    __shared__ float accs[4][64][32];      // 32 KB

    for (int p = tid; p < 4096; p += 256) {
        int c = p >> 5, d = p & 31;
        WqS[p] = qkv_w[c * 384 + h * 32 + d];
    }
    __syncthreads();

    // q = f2_row @ Wq_h  (bf16x8 vector loads)
    float q[32];
    #pragma unroll
    for (int d = 0; d < 32; ++d) q[d] = 0.f;
    const bf16* frow = f2 + (size_t)(b * NN + i) * 128;
    for (int cc = 0; cc < 16; ++cc) {
        float fv[8];
        load_bf16x8(frow + cc * 8, fv);
        #pragma unroll
        for (int u2 = 0; u2 < 8; ++u2) {
            const float* wrow = &WqS[(cc * 8 + u2) * 32];
            #pragma unroll
            for (int d = 0; d < 32; ++d) q[d] += fv[u2] * wrow[d];
        }
    }

    const int hoff = (kstride == 128) ? h * 32 : 0;
    const bf16* kb = kk + (size_t)b * NN * kstride + hoff;
    const bf16* vb = vv + (size_t)b * NN * kstride + hoff;
    const int j0 = sp * 512, j1 = j0 + 512;

    float m = -INFINITY;
    for (int j = j0; j < j1; ++j) {
        const bf16* kr = kb + (size_t)j * kstride;   // wave-uniform row
        float dsum = 0.f;
        #pragma unroll
        for (int d = 0; d < 32; ++d) dsum += q[d] * b2f(kr[d]);
        m = fmaxf(m, dsum * scale);
    }
    mred[sp][r] = m;
    __syncthreads();
    m = fmaxf(fmaxf(mred[0][r], mred[1][r]), fmaxf(mred[2][r], mred[3][r]));

    float l = 0.f;
    float a[32];
    #pragma unroll
    for (int d = 0; d < 32; ++d) a[d] = 0.f;
    for (int j = j0; j < j1; ++j) {
        const bf16* kr = kb + (size_t)j * kstride;
        float dsum = 0.f;
        #pragma unroll
        for (int d = 0; d < 32; ++d) dsum += q[d] * b2f(kr[d]);
        float p = __expf(dsum * scale - m);
        l += p;
        const bf16* vr = vb + (size_t)j * kstride;
        #pragma unroll
        for (int d = 0; d < 32; ++d) a[d] += p * b2f(vr[d]);
    }
    lred[sp][r] = l;
    #pragma unroll
    for (int d = 0; d < 32; ++d) accs[sp][r][d] = a[d];
    __syncthreads();

    const int row = tid >> 2;
    const int dbase = (tid & 3) * 8;
    const float denom = lred[0][row] + lred[1][row] + lred[2][row] + lred[3][row];
    bf16* orow = atth + (size_t)(b * NN + tile * 64 + row) * 128 + h * 32;
    #pragma unroll
    for (int uu = 0; uu < 8; ++uu) {
        int d = dbase + uu;
        float v = accs[0][row][d] + accs[1][row][d] + accs[2][row][d] + accs[3][row][d];
        orow[d] = __float2bfloat16(v / denom);
    }
}

// ---------------------------------------------------------------- fused out-proj + concat + refine MLP + log_softmax
__global__ __launch_bounds__(128) void final_kernel(
        const bf16* __restrict__ f2, const float* __restrict__ glob,
        const bf16* __restrict__ atth,
        const float* __restrict__ out_w, const float* __restrict__ out_b,
        const float* __restrict__ r1_w, const float* __restrict__ r1_b,
        const float* __restrict__ r2_w, const float* __restrict__ r2_b,
        const float* __restrict__ r3_w, const float* __restrict__ r3_b,
        float* __restrict__ out) {
    const int bn0 = blockIdx.x * 4;
    const int b = bn0 >> 11;
    const int tid = threadIdx.x;
    __shared__ float attin[4][128], comb[4][384], h1[4][128], h2[4][64];
    __shared__ float logits[4][20], lse[4];

    #pragma unroll
    for (int rr = 0; rr < 4; ++rr) {
        attin[rr][tid]      = b2f(atth[(size_t)(bn0 + rr) * 128 + tid]);
        comb[rr][tid]       = b2f(f2[(size_t)(bn0 + rr) * 128 + tid]);
        comb[rr][128 + tid] = glob[b * 128 + tid];
    }
    __syncthreads();
    {
        float a0 = 0.f, a1 = 0.f, a2 = 0.f, a3 = 0.f;
        for (int c = 0; c < 128; ++c) {
            float wv = out_w[c * 128 + tid];
            a0 += attin[0][c] * wv; a1 += attin[1][c] * wv;
            a2 += attin[2][c] * wv; a3 += attin[3][c] * wv;
        }
        float bb = out_b[tid];
        comb[0][256 + tid] = a0 + bb; comb[1][256 + tid] = a1 + bb;
        comb[2][256 + tid] = a2 + bb; comb[3][256 + tid] = a3 + bb;
    }
    __syncthreads();
    {
        float a0 = 0.f, a1 = 0.f, a2 = 0.f, a3 = 0.f;
        for (int c = 0; c < 384; ++c) {
            float wv = r1_w[c * 128 + tid];
            a0 += comb[0][c] * wv; a1 += comb[1][c] * wv;
            a2 += comb[2][c] * wv; a3 += comb[3][c] * wv;
        }
        float bb = r1_b[tid];
        h1[0][tid] = fmaxf(a0 + bb, 0.f); h1[1][tid] = fmaxf(a1 + bb, 0.f);
        h1[2][tid] = fmaxf(a2 + bb, 0.f); h1[3][tid] = fmaxf(a3 + bb, 0.f);
    }
    __syncthreads();
    if (tid < 64) {
        float a0 = 0.f, a1 = 0.f, a2 = 0.f, a3 = 0.f;
        for (int c = 0; c < 128; ++c) {
            float wv = r2_w[c * 64 + tid];
            a0 += h1[0][c] * wv; a1 += h1[1][c] * wv;
            a2 += h1[2][c] * wv; a3 += h1[3][c] * wv;
        }
        float bb = r2_b[tid];
        h2[0][tid] = fmaxf(a0 + bb, 0.f); h2[1][tid] = fmaxf(a1 + bb, 0.f);
        h2[2][tid] = fmaxf(a2 + bb, 0.f); h2[3][tid] = fmaxf(a3 + bb, 0.f);
    }
    __syncthreads();
    if (tid < 20) {
        float a0 = 0.f, a1 = 0.f, a2 = 0.f, a3 = 0.f;
        for (int c = 0; c < 64; ++c) {
            float wv = r3_w[c * 20 + tid];
            a0 += h2[0][c] * wv; a1 += h2[1][c] * wv;
            a2 += h2[2][c] * wv; a3 += h2[3][c] * wv;
        }
        float bb = r3_b[tid];
        logits[0][tid] = a0 + bb; logits[1][tid] = a1 + bb;
        logits[2][tid] = a2 + bb; logits[3][tid] = a3 + bb;
    }
    __syncthreads();
    if (tid < 4) {
        float m = -INFINITY;
        for (int u = 0; u < 20; ++u) m = fmaxf(m, logits[tid][u]);
        float s = 0.f;
        for (int u = 0; u < 20; ++u) s += expf(logits[tid][u] - m);
        lse[tid] = m + logf(s);
    }
    __syncthreads();
    if (tid < 80) {
        int rr = tid / 20, cls = tid % 20;
        out[(size_t)(bn0 + rr) * 20 + cls] = logits[rr][cls] - lse[rr];
    }
}

// ----------------------------------------------------------------------------
// Dual-path workspace probe:
//   Path A (ws >= 16.85 MB): f2[0,4) | kkA[4,8) | vvA[8,12) | atth[12,16) |
//     pmax/glob @16M; phase1-2 scratch (sqb/f1/knn/xT3) lives in [4,~9.3) and
//     dies before kvh writes. Attention = 1 launch, heads in grid (16 w/CU).
//   Path B (ws >= 10.56 MB): round-8 layout, per-head attention loop.
extern "C" void kernel_launch(void* const* d_in, const int* in_sizes, int n_in,
                              void* d_out, int out_size, void* d_ws, size_t ws_size,
                              hipStream_t stream) {
    const float* x      = (const float*)d_in[0];
    const float* ec1_w1 = (const float*)d_in[2];
    const float* ec1_b1 = (const float*)d_in[3];
    const float* ec1_w2 = (const float*)d_in[4];
    const float* ec1_b2 = (const float*)d_in[5];
    const float* ec2_w1 = (const float*)d_in[6];
    const float* ec2_b1 = (const float*)d_in[7];
    const float* ec2_w2 = (const float*)d_in[8];
    const float* ec2_b2 = (const float*)d_in[9];
    const float* qkv_w  = (const float*)d_in[10];
    const float* out_w  = (const float*)d_in[11];
    const float* out_b  = (const float*)d_in[12];
    const float* r1_w   = (const float*)d_in[13];
    const float* r1_b   = (const float*)d_in[14];
    const float* r2_w   = (const float*)d_in[15];
    const float* r2_b   = (const float*)d_in[16];
    const float* r3_w   = (const float*)d_in[17];
    const float* r3_b   = (const float*)d_in[18];
    float* out = (float*)d_out;

    const size_t MB = 1024 * 1024;
    const size_t NEED_B = 10555392;
    const size_t NEED_A = 16 * MB + 65536 + 4096;   // 16,846,848
    if (ws_size < NEED_B) return;
    const bool bigws = (ws_size >= NEED_A);

    char* base = (char*)d_ws;
    // common phase 1-3 buffers
    bf16*  f2   = (bf16*)(base);
    float* f1T  = (float*)(base);
    float* sqb  = (float*)(base + 4 * MB);
    float* f1   = (float*)(base + 4 * MB + 65536);
    u16*   knn  = (u16*)(base + 8 * MB + 65536);
    float* xT3  = (float*)(base + 8 * MB + 65536 + 655360);

    sqT_kernel<3><<<BBNN / 256, 256, 0, stream>>>(x, sqb, xT3);
    knn_fast_kernel<3, 3><<<BB * 256, 512, 0, stream>>>(x, xT3, sqb, knn);
    edgeconv_kernel<3, 64, false><<<BB * NN, 256, 0, stream>>>(
        x, knn, ec1_w1, ec1_b1, ec1_w2, ec1_b2, f1);

    sqT_kernel<64><<<BBNN / 256, 256, 0, stream>>>(f1, sqb, f1T);
    knn_fast_kernel<64, 8><<<BB * 256, 512, 0, stream>>>(f1, f1T, sqb, knn);
    edgeconv_kernel<64, 128, true><<<BB * NN, 256, 0, stream>>>(
        f1, knn, ec2_w1, ec2_b1, ec2_w2, ec2_b2, f2);

    if (bigws) {
        bf16*  kkA  = (bf16*)(base + 4 * MB);
        bf16*  vvA  = (bf16*)(base + 8 * MB);
        bf16*  atth = (bf16*)(base + 12 * MB);
        float* pmax = (float*)(base + 16 * MB);
        float* glob = (float*)(base + 16 * MB + 65536);

        gmax1_kernel<<<BB * 16, 128, 0, stream>>>(f2, pmax);
        gmax2_kernel<<<BB, 128, 0, stream>>>(pmax, glob);

        for (int h = 0; h < 4; ++h)
            kvh_kernel<<<BB * NN / 4, 256, 0, stream>>>(
                f2, qkv_w, kkA + h * 32, vvA + h * 32, h, 128);
        attnh_kernel<<<4 * BB * 32, 256, 0, stream>>>(
            f2, qkv_w, kkA, vvA, atth, -1, 128);

        final_kernel<<<BB * NN / 4, 128, 0, stream>>>(
            f2, glob, atth, out_w, out_b, r1_w, r1_b, r2_w, r2_b, r3_w, r3_b, out);
    } else {
        bf16*  kk   = (bf16*)(base + 4 * MB);
        bf16*  vv   = (bf16*)(base + 5 * MB);
        bf16*  atth = (bf16*)(base + 6 * MB);
        float* pmax = (float*)(base + 10 * MB);
        float* glob = (float*)(base + 10 * MB + 65536);

        gmax1_kernel<<<BB * 16, 128, 0, stream>>>(f2, pmax);
        gmax2_kernel<<<BB, 128, 0, stream>>>(pmax, glob);

        for (int h = 0; h < 4; ++h) {
            kvh_kernel<<<BB * NN / 4, 256, 0, stream>>>(f2, qkv_w, kk, vv, h, 32);
            attnh_kernel<<<BB * 32, 256, 0, stream>>>(f2, qkv_w, kk, vv, atth, h, 32);
        }

        final_kernel<<<BB * NN / 4, 128, 0, stream>>>(
            f2, glob, atth, out_w, out_b, r1_w, r1_b, r2_w, r2_b, r3_w, r3_b, out);
    }
}

// Round 10
// 1380.641 us; speedup vs baseline: 4.7405x; 1.6207x over previous
//
#include <hip/hip_runtime.h>
#include <hip/hip_bf16.h>

#define BB 8
#define NN 2048
#define KK 20
#define BBNN (BB * NN)

typedef __hip_bfloat16 bf16;
typedef unsigned short u16;
typedef __attribute__((ext_vector_type(8))) short short8;
typedef __attribute__((ext_vector_type(4))) float f32x4;

__device__ __forceinline__ float b2f(bf16 v) { return __bfloat162float(v); }

// load 8 contiguous bf16 (16B-aligned) -> 8 floats
__device__ __forceinline__ void load_bf16x8(const bf16* p, float* f) {
    uint4 u = *(const uint4*)p;
    f[0] = __uint_as_float(u.x << 16); f[1] = __uint_as_float(u.x & 0xffff0000u);
    f[2] = __uint_as_float(u.y << 16); f[3] = __uint_as_float(u.y & 0xffff0000u);
    f[4] = __uint_as_float(u.z << 16); f[5] = __uint_as_float(u.z & 0xffff0000u);
    f[6] = __uint_as_float(u.w << 16); f[7] = __uint_as_float(u.w & 0xffff0000u);
}

// ---------------------------------------------------------------- sq + transpose (fused)
template<int C>
__global__ __launch_bounds__(256) void sqT_kernel(const float* __restrict__ xin,
                                                  float* __restrict__ sq,
                                                  float* __restrict__ xT) {
    int t = blockIdx.x * 256 + threadIdx.x;
    if (t >= BBNN) return;
    const float* p = xin + (size_t)t * C;
    float s = 0.f;
    for (int c = 0; c < C; ++c) {
        float v = p[c];
        s += v * v;
        xT[(size_t)c * BBNN + t] = v;
    }
    sq[t] = s;
}

// ---------------------------------------------------------------- fast kNN v3 (spill-proof)
template<int C, int CH>
__global__ __launch_bounds__(512, 4) void knn_fast_kernel(
        const float* __restrict__ xrows,
        const float* __restrict__ xT,
        const float* __restrict__ sq,
        u16* __restrict__ idx_out) {
    __shared__ float xs[CH][256];
    const int blk = blockIdx.x;
    const int b = blk >> 8;
    const int tile = blk & 255;
    const int w = threadIdx.x >> 6;
    const int s = threadIdx.x & 63;
    const int i = tile * 8 + w;
    const int bn0 = b * NN;
    constexpr int NCH = C / CH;

    float d[32];
    #pragma unroll
    for (int r = 0; r < 32; ++r) d[r] = 0.f;

    const int qbase = (bn0 + i) * C;
    for (int ch = 0; ch < NCH; ++ch) {
        float xq[CH];
        #pragma unroll
        for (int cc = 0; cc < CH; ++cc) xq[cc] = xrows[qbase + ch * CH + cc];
        #pragma unroll 1
        for (int t = 0; t < 8; ++t) {
            __syncthreads();
            for (int p = threadIdx.x; p < CH * 256; p += 512) {
                int c = p >> 8, j = p & 255;
                xs[c][j] = xT[(size_t)(ch * CH + c) * BBNN + bn0 + t * 256 + j];
            }
            __syncthreads();
            float a0 = 0.f, a1 = 0.f, a2 = 0.f, a3 = 0.f;
            #pragma unroll
            for (int cc = 0; cc < CH; ++cc) {
                float q = xq[cc];
                a0 += q * xs[cc][s];
                a1 += q * xs[cc][64 + s];
                a2 += q * xs[cc][128 + s];
                a3 += q * xs[cc][192 + s];
            }
            d[t * 4 + 0] += a0; d[t * 4 + 1] += a1;
            d[t * 4 + 2] += a2; d[t * 4 + 3] += a3;
        }
    }
    const float sqi = sq[bn0 + i];
    #pragma unroll
    for (int r = 0; r < 32; ++r)
        d[r] = (sqi + sq[bn0 + r * 64 + s]) - 2.f * d[r];

    float ld = INFINITY; int lj = 0x7fffffff;
    #pragma unroll
    for (int r = 0; r < 32; ++r) {
        int j = r * 64 + s;
        if (d[r] < ld) { ld = d[r]; lj = j; }
    }
    for (int k = 0; k < KK; ++k) {
        float rd = ld; int rj = lj;
        #pragma unroll
        for (int m = 1; m < 64; m <<= 1) {
            float od = __shfl_xor(rd, m);
            int   oj = __shfl_xor(rj, m);
            if (od < rd || (od == rd && oj < rj)) { rd = od; rj = oj; }
        }
        if (s == 0) idx_out[(size_t)(bn0 + i) * KK + k] = (u16)rj;
        if (k + 1 < KK) {
            if (s == (rj & 63)) {
                int rr = rj >> 6;
                ld = INFINITY; lj = 0x7fffffff;
                #pragma unroll
                for (int r = 0; r < 32; ++r) {
                    if (r == rr) d[r] = INFINITY;
                    int j = r * 64 + s;
                    if (d[r] < ld) { ld = d[r]; lj = j; }
                }
            }
        }
    }
}

// ---------------------------------------------------------------- EdgeConv v2: parallel over (k, h)
template<int CIN, int COUT, bool BF16OUT>
__global__ __launch_bounds__(256) void edgeconv_kernel(
        const float* __restrict__ xin, const u16* __restrict__ knn,
        const float* __restrict__ w1, const float* __restrict__ b1,
        const float* __restrict__ w2, const float* __restrict__ b2,
        void* __restrict__ out) {
    const int bn = blockIdx.x;
    const int b = bn >> 11;
    const int tid = threadIdx.x;
    constexpr int SPLIT = 256 / COUT;
    constexpr int KPS = KK / SPLIT;
    __shared__ bf16 w1s[2 * CIN * 64];
    __shared__ bf16 w2s[64 * COUT];
    __shared__ float b1s[64], xi_s[CIN], base1[64];
    __shared__ float ediff[KK][CIN];
    __shared__ float h1s[KK][64];
    __shared__ float pm[SPLIT][COUT];
    __shared__ int js[KK];

    for (int p = tid; p < 2 * CIN * 64; p += 256) w1s[p] = __float2bfloat16(w1[p]);
    for (int p = tid; p < 64 * COUT; p += 256)    w2s[p] = __float2bfloat16(w2[p]);
    if (tid < 64) b1s[tid] = b1[tid];
    if (tid < CIN) xi_s[tid] = xin[(size_t)bn * CIN + tid];
    if (tid >= 64 && tid < 64 + KK) {
        int j = knn[bn * KK + (tid - 64)];
        js[tid - 64] = (j < NN) ? j : 0;
    }
    __syncthreads();

    for (int p = tid; p < KK * CIN; p += 256) {
        int k = p / CIN, c = p % CIN;
        ediff[k][c] = xin[((size_t)(b * NN + js[k])) * CIN + c] - xi_s[c];
    }
    if (tid < 64) {
        float a = b1s[tid];
        for (int c = 0; c < CIN; ++c) a += xi_s[c] * b2f(w1s[c * 64 + tid]);
        base1[tid] = a;
    }
    __syncthreads();

    for (int p = tid; p < KK * 64; p += 256) {
        int k = p >> 6, h = p & 63;
        float a = base1[h];
        for (int c = 0; c < CIN; ++c) a += ediff[k][c] * b2f(w1s[(CIN + c) * 64 + h]);
        h1s[k][h] = fmaxf(a, 0.f);
    }
    __syncthreads();

    {
        int o = tid % COUT, sp = tid / COUT;
        float mx = -INFINITY;
        for (int kk2 = 0; kk2 < KPS; ++kk2) {
            int k = sp * KPS + kk2;
            float a = 0.f;
            for (int c = 0; c < 64; ++c) a += h1s[k][c] * b2f(w2s[c * COUT + o]);
            mx = fmaxf(mx, a);
        }
        pm[sp][o] = mx;
    }
    __syncthreads();
    if (tid < COUT) {
        float mx = pm[0][tid];
        #pragma unroll
        for (int s2 = 1; s2 < SPLIT; ++s2) mx = fmaxf(mx, pm[s2][tid]);
        mx += b2[tid];
        if (BF16OUT) ((bf16*)out)[(size_t)bn * COUT + tid] = __float2bfloat16(mx);
        else         ((float*)out)[(size_t)bn * COUT + tid] = mx;
    }
}

// ---------------------------------------------------------------- global max over N (2-stage)
__global__ __launch_bounds__(128) void gmax1_kernel(const bf16* __restrict__ f2,
                                                    float* __restrict__ pmax) {
    const int b = blockIdx.x >> 4, ch = blockIdx.x & 15, c = threadIdx.x;
    float m = -INFINITY;
    const bf16* base = f2 + ((size_t)(b * NN + ch * 128)) * 128 + c;
    for (int n = 0; n < 128; ++n) m = fmaxf(m, b2f(base[(size_t)n * 128]));
    pmax[blockIdx.x * 128 + c] = m;
}

__global__ __launch_bounds__(128) void gmax2_kernel(const float* __restrict__ pmax,
                                                    float* __restrict__ glob) {
    const int b = blockIdx.x, c = threadIdx.x;
    float m = -INFINITY;
    for (int ch = 0; ch < 16; ++ch) m = fmaxf(m, pmax[(b * 16 + ch) * 128 + c]);
    glob[b * 128 + c] = m;
}

// ---------------------------------------------------------------- K + V^T for all heads (Path A)
// grid = 4 heads * BBNN/4. Writes K per-head [B][H][2048][32] and V transposed
// [B][H][32][2048] (via LDS so VT stores are 4-consecutive-n chunks).
__global__ __launch_bounds__(256) void kvt_kernel(const bf16* __restrict__ f2,
                                                  const float* __restrict__ qkv_w,
                                                  bf16* __restrict__ kk,
                                                  bf16* __restrict__ vt) {
    const int blk = blockIdx.x;
    const int h = blk >> 12;
    const int rg = blk & 4095;
    const int bn0 = rg * 4;
    const int b = bn0 >> 11, n0 = bn0 & 2047;
    const int tid = threadIdx.x;
    __shared__ float Ws[2][128][32];
    __shared__ float f2s[4][128];
    __shared__ float vbuf[4][32];
    for (int p = tid; p < 2 * 128 * 32; p += 256) {
        int kv = p >> 12, c = (p >> 5) & 127, d = p & 31;
        Ws[kv][c][d] = qkv_w[c * 384 + 128 + kv * 128 + h * 32 + d];
    }
    for (int p = tid; p < 4 * 128; p += 256) {
        int rr = p >> 7, c = p & 127;
        f2s[rr][c] = b2f(f2[(size_t)(bn0 + rr) * 128 + c]);
    }
    __syncthreads();
    const int rr = tid >> 6, u = tid & 63, kv = u >> 5, d = u & 31;
    float acc = 0.f;
    for (int c = 0; c < 128; ++c) acc += f2s[rr][c] * Ws[kv][c][d];
    if (kv == 0)
        kk[((size_t)(b * 4 + h) * 2048 + n0 + rr) * 32 + d] = __float2bfloat16(acc);
    else
        vbuf[rr][d] = acc;
    __syncthreads();
    if (tid < 128) {
        int dd = tid >> 2, r2 = tid & 3;
        vt[((size_t)(b * 4 + h) * 32 + dd) * 2048 + n0 + r2] = __float2bfloat16(vbuf[r2][dd]);
    }
}

// ---------------------------------------------------------------- MFMA flash attention (Path A)
// grid = B*H*32 q-tiles of 64 rows; 4 waves x 16 q-rows. No-max softmax
// (scores << 80 by construction: weights scale 0.05). P transits LDS
// (C-layout -> A-layout, m120-verified), row-sums via ones-MFMA.
__global__ __launch_bounds__(256) void attn_mfma_kernel(
        const bf16* __restrict__ f2, const float* __restrict__ qkv_w,
        const bf16* __restrict__ kk, const bf16* __restrict__ vt,
        bf16* __restrict__ atth) {
    const int blk = blockIdx.x;
    const int tile = blk & 31;
    const int h = (blk >> 5) & 3;
    const int b = blk >> 7;
    const int tid = threadIdx.x;
    const int w = tid >> 6;
    const int lane = tid & 63;
    const int lq = lane & 15;
    const int quad = lane >> 4;
    const float scale = 0.17677669529663687f;  // 32^-0.5

    __shared__ __align__(16) bf16 WqT[32][128];       // [d][c]  8 KB
    __shared__ __align__(16) bf16 pbuf[4][2][16][32]; // per-wave dbl-buf 8 KB

    for (int p = tid; p < 4096; p += 256) {
        int c = p >> 5, d = p & 31;
        WqT[d][c] = __float2bfloat16(qkv_w[c * 384 + h * 32 + d]);
    }
    __syncthreads();

    // ---- Q = f2_tile @ Wq (M=16, N=32, K=128), scale folded in
    const int q0 = tile * 64 + w * 16;
    const bf16* fbase = f2 + ((size_t)(b * NN + q0 + lq)) * 128;
    f32x4 qc0 = {0.f, 0.f, 0.f, 0.f}, qc1 = {0.f, 0.f, 0.f, 0.f};
    #pragma unroll
    for (int kc = 0; kc < 4; ++kc) {
        short8 af = *(const short8*)(fbase + kc * 32 + quad * 8);
        short8 b0 = *(const short8*)(&WqT[lq][kc * 32 + quad * 8]);
        short8 b1 = *(const short8*)(&WqT[16 + lq][kc * 32 + quad * 8]);
        qc0 = __builtin_amdgcn_mfma_f32_16x16x32_bf16(af, b0, qc0, 0, 0, 0);
        qc1 = __builtin_amdgcn_mfma_f32_16x16x32_bf16(af, b1, qc1, 0, 0, 0);
    }
    {   // C-layout -> [16 q][32 d] in LDS -> A-frag
        bf16* pw = &pbuf[w][0][0][0];
        #pragma unroll
        for (int r = 0; r < 4; ++r) {
            int qq = quad * 4 + r;
            pw[qq * 32 + lq]      = __float2bfloat16(qc0[r] * scale);
            pw[qq * 32 + 16 + lq] = __float2bfloat16(qc1[r] * scale);
        }
    }
    __syncthreads();
    const short8 qfrag = *(const short8*)(&pbuf[w][0][lq][quad * 8]);
    __syncthreads();   // protect pbuf[w][0] (WAR) before chunk 0 writes it

    const bf16* kb = kk + (size_t)(b * 4 + h) * 2048 * 32;
    const bf16* vb = vt + (size_t)(b * 4 + h) * 32 * 2048;
    f32x4 o0 = {0.f, 0.f, 0.f, 0.f}, o1 = {0.f, 0.f, 0.f, 0.f};
    f32x4 lsum = {0.f, 0.f, 0.f, 0.f};
    const short8 ones = {(short)0x3F80, (short)0x3F80, (short)0x3F80, (short)0x3F80,
                         (short)0x3F80, (short)0x3F80, (short)0x3F80, (short)0x3F80};

    for (int ch = 0; ch < 64; ++ch) {
        const int j0 = ch * 32;
        short8 kf0 = *(const short8*)(kb + (size_t)(j0 + lq) * 32 + quad * 8);
        short8 kf1 = *(const short8*)(kb + (size_t)(j0 + 16 + lq) * 32 + quad * 8);
        f32x4 z = {0.f, 0.f, 0.f, 0.f};
        f32x4 s0 = __builtin_amdgcn_mfma_f32_16x16x32_bf16(qfrag, kf0, z, 0, 0, 0);
        f32x4 s1 = __builtin_amdgcn_mfma_f32_16x16x32_bf16(qfrag, kf1, z, 0, 0, 0);
        bf16* pw = &pbuf[w][ch & 1][0][0];
        #pragma unroll
        for (int r = 0; r < 4; ++r) {
            int qq = quad * 4 + r;
            pw[qq * 32 + lq]      = __float2bfloat16(__expf(s0[r]));
            pw[qq * 32 + 16 + lq] = __float2bfloat16(__expf(s1[r]));
        }
        __syncthreads();
        short8 pf = *(const short8*)(pw + lq * 32 + quad * 8);
        short8 vf0 = *(const short8*)(vb + (size_t)lq * 2048 + j0 + quad * 8);
        short8 vf1 = *(const short8*)(vb + (size_t)(16 + lq) * 2048 + j0 + quad * 8);
        o0   = __builtin_amdgcn_mfma_f32_16x16x32_bf16(pf, vf0, o0, 0, 0, 0);
        o1   = __builtin_amdgcn_mfma_f32_16x16x32_bf16(pf, vf1, o1, 0, 0, 0);
        lsum = __builtin_amdgcn_mfma_f32_16x16x32_bf16(pf, ones, lsum, 0, 0, 0);
    }

    #pragma unroll
    for (int r = 0; r < 4; ++r) {
        int row = q0 + quad * 4 + r;
        float inv = 1.f / lsum[r];
        bf16* orow = atth + ((size_t)(b * NN + row)) * 128 + h * 32;
        orow[lq]      = __float2bfloat16(o0[r] * inv);
        orow[16 + lq] = __float2bfloat16(o1[r] * inv);
    }
}

// ---------------------------------------------------------------- K_h, V_h per head (Path B fallback)
__global__ __launch_bounds__(256) void kvh_kernel(const bf16* __restrict__ f2,
                                                  const float* __restrict__ qkv_w,
                                                  bf16* __restrict__ kk,
                                                  bf16* __restrict__ vv,
                                                  int h, int ostride) {
    const int bn0 = blockIdx.x * 4;
    const int tid = threadIdx.x;
    __shared__ float Ws[2][128][32];
    __shared__ float f2s[4][128];
    for (int p = tid; p < 2 * 128 * 32; p += 256) {
        int kv = p >> 12, c = (p >> 5) & 127, d = p & 31;
        Ws[kv][c][d] = qkv_w[c * 384 + 128 + kv * 128 + h * 32 + d];
    }
    for (int p = tid; p < 4 * 128; p += 256) {
        int rr = p >> 7, c = p & 127;
        f2s[rr][c] = b2f(f2[(size_t)(bn0 + rr) * 128 + c]);
    }
    __syncthreads();
    const int rr = tid >> 6, u = tid & 63, kv = u >> 5, d = u & 31;
    float acc = 0.f;
    for (int c = 0; c < 128; ++c) acc += f2s[rr][c] * Ws[kv][c][d];
    bf16* dst = kv ? vv : kk;
    dst[(size_t)(bn0 + rr) * ostride + d] = __float2bfloat16(acc);
}

// ---------------------------------------------------------------- VALU attention (Path B fallback)
__global__ __launch_bounds__(256) void attnh_kernel(const bf16* __restrict__ f2,
                                                    const float* __restrict__ qkv_w,
                                                    const bf16* __restrict__ kk,
                                                    const bf16* __restrict__ vv,
                                                    bf16* __restrict__ atth,
                                                    int h_in, int kstride) {
    int blk = blockIdx.x;
    int h;
    if (h_in < 0) { h = blk >> 8; blk &= 255; } else { h = h_in; }
    const int tile = blk & 31;
    const int b = blk >> 5;
    const int tid = threadIdx.x;
    const int r = tid & 63;
    const int sp = tid >> 6;
    const int i = tile * 64 + r;
    const float scale = 0.17677669529663687f;
    __shared__ float WqS[128 * 32];
    __shared__ float mred[4][64], lred[4][64];
    __shared__ float accs[4][64][32];

    for (int p = tid; p < 4096; p += 256) {
        int c = p >> 5, d = p & 31;
        WqS[p] = qkv_w[c * 384 + h * 32 + d];
    }
    __syncthreads();

    float q[32];
    #pragma unroll
    for (int d = 0; d < 32; ++d) q[d] = 0.f;
    const bf16* frow = f2 + (size_t)(b * NN + i) * 128;
    for (int cc = 0; cc < 16; ++cc) {
        float fv[8];
        load_bf16x8(frow + cc * 8, fv);
        #pragma unroll
        for (int u2 = 0; u2 < 8; ++u2) {
            const float* wrow = &WqS[(cc * 8 + u2) * 32];
            #pragma unroll
            for (int d = 0; d < 32; ++d) q[d] += fv[u2] * wrow[d];
        }
    }

    const int hoff = (kstride == 128) ? h * 32 : 0;
    const bf16* kb = kk + (size_t)b * NN * kstride + hoff;
    const bf16* vb = vv + (size_t)b * NN * kstride + hoff;
    const int j0 = sp * 512, j1 = j0 + 512;

    float m = -INFINITY;
    for (int j = j0; j < j1; ++j) {
        const bf16* kr = kb + (size_t)j * kstride;
        float dsum = 0.f;
        #pragma unroll
        for (int d = 0; d < 32; ++d) dsum += q[d] * b2f(kr[d]);
        m = fmaxf(m, dsum * scale);
    }
    mred[sp][r] = m;
    __syncthreads();
    m = fmaxf(fmaxf(mred[0][r], mred[1][r]), fmaxf(mred[2][r], mred[3][r]));

    float l = 0.f;
    float a[32];
    #pragma unroll
    for (int d = 0; d < 32; ++d) a[d] = 0.f;
    for (int j = j0; j < j1; ++j) {
        const bf16* kr = kb + (size_t)j * kstride;
        float dsum = 0.f;
        #pragma unroll
        for (int d = 0; d < 32; ++d) dsum += q[d] * b2f(kr[d]);
        float p = __expf(dsum * scale - m);
        l += p;
        const bf16* vr = vb + (size_t)j * kstride;
        #pragma unroll
        for (int d = 0; d < 32; ++d) a[d] += p * b2f(vr[d]);
    }
    lred[sp][r] = l;
    #pragma unroll
    for (int d = 0; d < 32; ++d) accs[sp][r][d] = a[d];
    __syncthreads();

    const int row = tid >> 2;
    const int dbase = (tid & 3) * 8;
    const float denom = lred[0][row] + lred[1][row] + lred[2][row] + lred[3][row];
    bf16* orow = atth + (size_t)(b * NN + tile * 64 + row) * 128 + h * 32;
    #pragma unroll
    for (int uu = 0; uu < 8; ++uu) {
        int d = dbase + uu;
        float v = accs[0][row][d] + accs[1][row][d] + accs[2][row][d] + accs[3][row][d];
        orow[d] = __float2bfloat16(v / denom);
    }
}

// ---------------------------------------------------------------- fused out-proj + concat + refine MLP + log_softmax
__global__ __launch_bounds__(128) void final_kernel(
        const bf16* __restrict__ f2, const float* __restrict__ glob,
        const bf16* __restrict__ atth,
        const float* __restrict__ out_w, const float* __restrict__ out_b,
        const float* __restrict__ r1_w, const float* __restrict__ r1_b,
        const float* __restrict__ r2_w, const float* __restrict__ r2_b,
        const float* __restrict__ r3_w, const float* __restrict__ r3_b,
        float* __restrict__ out) {
    const int bn0 = blockIdx.x * 4;
    const int b = bn0 >> 11;
    const int tid = threadIdx.x;
    __shared__ float attin[4][128], comb[4][384], h1[4][128], h2[4][64];
    __shared__ float logits[4][20], lse[4];

    #pragma unroll
    for (int rr = 0; rr < 4; ++rr) {
        attin[rr][tid]      = b2f(atth[(size_t)(bn0 + rr) * 128 + tid]);
        comb[rr][tid]       = b2f(f2[(size_t)(bn0 + rr) * 128 + tid]);
        comb[rr][128 + tid] = glob[b * 128 + tid];
    }
    __syncthreads();
    {
        float a0 = 0.f, a1 = 0.f, a2 = 0.f, a3 = 0.f;
        for (int c = 0; c < 128; ++c) {
            float wv = out_w[c * 128 + tid];
            a0 += attin[0][c] * wv; a1 += attin[1][c] * wv;
            a2 += attin[2][c] * wv; a3 += attin[3][c] * wv;
        }
        float bb = out_b[tid];
        comb[0][256 + tid] = a0 + bb; comb[1][256 + tid] = a1 + bb;
        comb[2][256 + tid] = a2 + bb; comb[3][256 + tid] = a3 + bb;
    }
    __syncthreads();
    {
        float a0 = 0.f, a1 = 0.f, a2 = 0.f, a3 = 0.f;
        for (int c = 0; c < 384; ++c) {
            float wv = r1_w[c * 128 + tid];
            a0 += comb[0][c] * wv; a1 += comb[1][c] * wv;
            a2 += comb[2][c] * wv; a3 += comb[3][c] * wv;
        }
        float bb = r1_b[tid];
        h1[0][tid] = fmaxf(a0 + bb, 0.f); h1[1][tid] = fmaxf(a1 + bb, 0.f);
        h1[2][tid] = fmaxf(a2 + bb, 0.f); h1[3][tid] = fmaxf(a3 + bb, 0.f);
    }
    __syncthreads();
    if (tid < 64) {
        float a0 = 0.f, a1 = 0.f, a2 = 0.f, a3 = 0.f;
        for (int c = 0; c < 128; ++c) {
            float wv = r2_w[c * 64 + tid];
            a0 += h1[0][c] * wv; a1 += h1[1][c] * wv;
            a2 += h1[2][c] * wv; a3 += h1[3][c] * wv;
        }
        float bb = r2_b[tid];
        h2[0][tid] = fmaxf(a0 + bb, 0.f); h2[1][tid] = fmaxf(a1 + bb, 0.f);
        h2[2][tid] = fmaxf(a2 + bb, 0.f); h2[3][tid] = fmaxf(a3 + bb, 0.f);
    }
    __syncthreads();
    if (tid < 20) {
        float a0 = 0.f, a1 = 0.f, a2 = 0.f, a3 = 0.f;
        for (int c = 0; c < 64; ++c) {
            float wv = r3_w[c * 20 + tid];
            a0 += h2[0][c] * wv; a1 += h2[1][c] * wv;
            a2 += h2[2][c] * wv; a3 += h2[3][c] * wv;
        }
        float bb = r3_b[tid];
        logits[0][tid] = a0 + bb; logits[1][tid] = a1 + bb;
        logits[2][tid] = a2 + bb; logits[3][tid] = a3 + bb;
    }
    __syncthreads();
    if (tid < 4) {
        float m = -INFINITY;
        for (int u = 0; u < 20; ++u) m = fmaxf(m, logits[tid][u]);
        float s = 0.f;
        for (int u = 0; u < 20; ++u) s += expf(logits[tid][u] - m);
        lse[tid] = m + logf(s);
    }
    __syncthreads();
    if (tid < 80) {
        int rr = tid / 20, cls = tid % 20;
        out[(size_t)(bn0 + rr) * 20 + cls] = logits[rr][cls] - lse[rr];
    }
}

// ----------------------------------------------------------------------------
// Path A (ws >= 16.85 MB, proven): f2[0,4) | kk[4,8) per-head | VT[8,12) |
//   atth[12,16) | pmax/glob @16M. Phase1-2 scratch dies before kk written.
// Path B fallback: round-8 layout + per-head VALU attention.
extern "C" void kernel_launch(void* const* d_in, const int* in_sizes, int n_in,
                              void* d_out, int out_size, void* d_ws, size_t ws_size,
                              hipStream_t stream) {
    const float* x      = (const float*)d_in[0];
    const float* ec1_w1 = (const float*)d_in[2];
    const float* ec1_b1 = (const float*)d_in[3];
    const float* ec1_w2 = (const float*)d_in[4];
    const float* ec1_b2 = (const float*)d_in[5];
    const float* ec2_w1 = (const float*)d_in[6];
    const float* ec2_b1 = (const float*)d_in[7];
    const float* ec2_w2 = (const float*)d_in[8];
    const float* ec2_b2 = (const float*)d_in[9];
    const float* qkv_w  = (const float*)d_in[10];
    const float* out_w  = (const float*)d_in[11];
    const float* out_b  = (const float*)d_in[12];
    const float* r1_w   = (const float*)d_in[13];
    const float* r1_b   = (const float*)d_in[14];
    const float* r2_w   = (const float*)d_in[15];
    const float* r2_b   = (const float*)d_in[16];
    const float* r3_w   = (const float*)d_in[17];
    const float* r3_b   = (const float*)d_in[18];
    float* out = (float*)d_out;

    const size_t MB = 1024 * 1024;
    const size_t NEED_B = 10555392;
    const size_t NEED_A = 16 * MB + 65536 + 4096;
    if (ws_size < NEED_B) return;
    const bool bigws = (ws_size >= NEED_A);

    char* base = (char*)d_ws;
    bf16*  f2   = (bf16*)(base);
    float* f1T  = (float*)(base);
    float* sqb  = (float*)(base + 4 * MB);
    float* f1   = (float*)(base + 4 * MB + 65536);
    u16*   knn  = (u16*)(base + 8 * MB + 65536);
    float* xT3  = (float*)(base + 8 * MB + 65536 + 655360);

    sqT_kernel<3><<<BBNN / 256, 256, 0, stream>>>(x, sqb, xT3);
    knn_fast_kernel<3, 3><<<BB * 256, 512, 0, stream>>>(x, xT3, sqb, knn);
    edgeconv_kernel<3, 64, false><<<BB * NN, 256, 0, stream>>>(
        x, knn, ec1_w1, ec1_b1, ec1_w2, ec1_b2, f1);

    sqT_kernel<64><<<BBNN / 256, 256, 0, stream>>>(f1, sqb, f1T);
    knn_fast_kernel<64, 8><<<BB * 256, 512, 0, stream>>>(f1, f1T, sqb, knn);
    edgeconv_kernel<64, 128, true><<<BB * NN, 256, 0, stream>>>(
        f1, knn, ec2_w1, ec2_b1, ec2_w2, ec2_b2, f2);

    if (bigws) {
        bf16*  kkA  = (bf16*)(base + 4 * MB);
        bf16*  vtA  = (bf16*)(base + 8 * MB);
        bf16*  atth = (bf16*)(base + 12 * MB);
        float* pmax = (float*)(base + 16 * MB);
        float* glob = (float*)(base + 16 * MB + 65536);

        gmax1_kernel<<<BB * 16, 128, 0, stream>>>(f2, pmax);
        gmax2_kernel<<<BB, 128, 0, stream>>>(pmax, glob);

        kvt_kernel<<<4 * BB * NN / 4, 256, 0, stream>>>(f2, qkv_w, kkA, vtA);
        attn_mfma_kernel<<<BB * 4 * 32, 256, 0, stream>>>(f2, qkv_w, kkA, vtA, atth);

        final_kernel<<<BB * NN / 4, 128, 0, stream>>>(
            f2, glob, atth, out_w, out_b, r1_w, r1_b, r2_w, r2_b, r3_w, r3_b, out);
    } else {
        bf16*  kk   = (bf16*)(base + 4 * MB);
        bf16*  vv   = (bf16*)(base + 5 * MB);
        bf16*  atth = (bf16*)(base + 6 * MB);
        float* pmax = (float*)(base + 10 * MB);
        float* glob = (float*)(base + 10 * MB + 65536);

        gmax1_kernel<<<BB * 16, 128, 0, stream>>>(f2, pmax);
        gmax2_kernel<<<BB, 128, 0, stream>>>(pmax, glob);

        for (int h = 0; h < 4; ++h) {
            kvh_kernel<<<BB * NN / 4, 256, 0, stream>>>(f2, qkv_w, kk, vv, h, 32);
            attnh_kernel<<<BB * 32, 256, 0, stream>>>(f2, qkv_w, kk, vv, atth, h, 32);
        }

        final_kernel<<<BB * NN / 4, 128, 0, stream>>>(
            f2, glob, atth, out_w, out_b, r1_w, r1_b, r2_w, r2_b, r3_w, r3_b, out);
    }
}

// Round 11
// 1144.904 us; speedup vs baseline: 5.7165x; 1.2059x over previous
//
#include <hip/hip_runtime.h>
#include <hip/hip_bf16.h>

#define BB 8
#define NN 2048
#define KK 20
#define BBNN (BB * NN)

typedef __hip_bfloat16 bf16;
typedef unsigned short u16;
typedef __attribute__((ext_vector_type(8))) short short8;
typedef __attribute__((ext_vector_type(4))) float f32x4;

__device__ __forceinline__ float b2f(bf16 v) { return __bfloat162float(v); }

// load 8 contiguous bf16 (16B-aligned) -> 8 floats
__device__ __forceinline__ void load_bf16x8(const bf16* p, float* f) {
    uint4 u = *(const uint4*)p;
    f[0] = __uint_as_float(u.x << 16); f[1] = __uint_as_float(u.x & 0xffff0000u);
    f[2] = __uint_as_float(u.y << 16); f[3] = __uint_as_float(u.y & 0xffff0000u);
    f[4] = __uint_as_float(u.z << 16); f[5] = __uint_as_float(u.z & 0xffff0000u);
    f[6] = __uint_as_float(u.w << 16); f[7] = __uint_as_float(u.w & 0xffff0000u);
}

// ---------------------------------------------------------------- sq + transpose (fused)
template<int C>
__global__ __launch_bounds__(256) void sqT_kernel(const float* __restrict__ xin,
                                                  float* __restrict__ sq,
                                                  float* __restrict__ xT) {
    int t = blockIdx.x * 256 + threadIdx.x;
    if (t >= BBNN) return;
    const float* p = xin + (size_t)t * C;
    float s = 0.f;
    for (int c = 0; c < C; ++c) {
        float v = p[c];
        s += v * v;
        xT[(size_t)c * BBNN + t] = v;
    }
    sq[t] = s;
}

// ---------------------------------------------------------------- fast kNN v4
// Block = 512 thr = 8 waves; each wave owns TWO queries (16 q/block).
// Phase A: j-tiles of 256 staged to LDS; lane s owns j = t*256 + 4s + {0..3}
// -> ONE ds_read_b128 per (cc, 4 j) reused for BOTH queries (8x fewer LDS
// instructions than v3's per-MAC ds_read_b32). Per-pair dot arithmetic keeps
// the exact c-order of the passing kernels -> bit-identical distances.
// Phase B: per-query 20-round lexicographic (d,j) argmin in registers.
// VGPR budget: dA+dB=64 + ~30 misc < 128 cap of (512,4) -> no spill.
template<int C, int CH>
__global__ __launch_bounds__(512, 4) void knn_fast_kernel(
        const float* __restrict__ xrows,   // [BBNN][C] row-major (query reads)
        const float* __restrict__ xT,      // [C][BBNN] transposed (neighbor reads)
        const float* __restrict__ sq,
        u16* __restrict__ idx_out) {
    __shared__ __align__(16) float xs[CH][256];
    const int blk = blockIdx.x;            // BB * 128
    const int b = blk >> 7;
    const int tile = blk & 127;
    const int w = threadIdx.x >> 6;
    const int s = threadIdx.x & 63;
    const int iA = tile * 16 + w * 2;      // first query of this wave
    const int bn0 = b * NN;
    constexpr int NCH = C / CH;

    float dA[32], dB[32];
    #pragma unroll
    for (int r = 0; r < 32; ++r) { dA[r] = 0.f; dB[r] = 0.f; }

    const int qbaseA = __builtin_amdgcn_readfirstlane((bn0 + iA) * C);
    for (int ch = 0; ch < NCH; ++ch) {
        float xqA[CH], xqB[CH];
        #pragma unroll
        for (int cc = 0; cc < CH; ++cc) {
            xqA[cc] = xrows[qbaseA + ch * CH + cc];
            xqB[cc] = xrows[qbaseA + C + ch * CH + cc];
        }
        #pragma unroll 1
        for (int t = 0; t < 8; ++t) {
            __syncthreads();
            for (int p = threadIdx.x; p < CH * 64; p += 512) {
                int c = p >> 6, j4 = (p & 63) << 2;
                *(float4*)&xs[c][j4] =
                    *(const float4*)(xT + (size_t)(ch * CH + c) * BBNN + bn0 + t * 256 + j4);
            }
            __syncthreads();
            float aA0 = 0.f, aA1 = 0.f, aA2 = 0.f, aA3 = 0.f;
            float aB0 = 0.f, aB1 = 0.f, aB2 = 0.f, aB3 = 0.f;
            #pragma unroll
            for (int cc = 0; cc < CH; ++cc) {
                float4 xv = *(const float4*)&xs[cc][s * 4];
                float qA = xqA[cc], qB = xqB[cc];
                aA0 += qA * xv.x; aA1 += qA * xv.y; aA2 += qA * xv.z; aA3 += qA * xv.w;
                aB0 += qB * xv.x; aB1 += qB * xv.y; aB2 += qB * xv.z; aB3 += qB * xv.w;
            }
            dA[t * 4 + 0] += aA0; dA[t * 4 + 1] += aA1;
            dA[t * 4 + 2] += aA2; dA[t * 4 + 3] += aA3;
            dB[t * 4 + 0] += aB0; dB[t * 4 + 1] += aB1;
            dB[t * 4 + 2] += aB2; dB[t * 4 + 3] += aB3;
        }
    }
    const float sqiA = sq[bn0 + iA];
    const float sqiB = sq[bn0 + iA + 1];
    #pragma unroll
    for (int r = 0; r < 32; ++r) {
        int j = ((r >> 2) << 8) + (s << 2) + (r & 3);
        float sqj = sq[bn0 + j];
        dA[r] = (sqiA + sqj) - 2.f * dA[r];
        dB[r] = (sqiB + sqj) - 2.f * dB[r];
    }

    // ---- phase B: query A then query B (j(r) ascending in r -> strict < ok)
    {
        float ld = INFINITY; int lj = 0x7fffffff;
        #pragma unroll
        for (int r = 0; r < 32; ++r) {
            int j = ((r >> 2) << 8) + (s << 2) + (r & 3);
            if (dA[r] < ld) { ld = dA[r]; lj = j; }
        }
        for (int k = 0; k < KK; ++k) {
            float rd = ld; int rj = lj;
            #pragma unroll
            for (int m = 1; m < 64; m <<= 1) {
                float od = __shfl_xor(rd, m);
                int   oj = __shfl_xor(rj, m);
                if (od < rd || (od == rd && oj < rj)) { rd = od; rj = oj; }
            }
            if (s == 0) idx_out[(size_t)(bn0 + iA) * KK + k] = (u16)rj;
            if (k + 1 < KK) {
                if (s == ((rj & 255) >> 2)) {
                    int rr = ((rj >> 8) << 2) + (rj & 3);
                    ld = INFINITY; lj = 0x7fffffff;
                    #pragma unroll
                    for (int r = 0; r < 32; ++r) {
                        if (r == rr) dA[r] = INFINITY;
                        int j = ((r >> 2) << 8) + (s << 2) + (r & 3);
                        if (dA[r] < ld) { ld = dA[r]; lj = j; }
                    }
                }
            }
        }
    }
    {
        float ld = INFINITY; int lj = 0x7fffffff;
        #pragma unroll
        for (int r = 0; r < 32; ++r) {
            int j = ((r >> 2) << 8) + (s << 2) + (r & 3);
            if (dB[r] < ld) { ld = dB[r]; lj = j; }
        }
        for (int k = 0; k < KK; ++k) {
            float rd = ld; int rj = lj;
            #pragma unroll
            for (int m = 1; m < 64; m <<= 1) {
                float od = __shfl_xor(rd, m);
                int   oj = __shfl_xor(rj, m);
                if (od < rd || (od == rd && oj < rj)) { rd = od; rj = oj; }
            }
            if (s == 0) idx_out[(size_t)(bn0 + iA + 1) * KK + k] = (u16)rj;
            if (k + 1 < KK) {
                if (s == ((rj & 255) >> 2)) {
                    int rr = ((rj >> 8) << 2) + (rj & 3);
                    ld = INFINITY; lj = 0x7fffffff;
                    #pragma unroll
                    for (int r = 0; r < 32; ++r) {
                        if (r == rr) dB[r] = INFINITY;
                        int j = ((r >> 2) << 8) + (s << 2) + (r & 3);
                        if (dB[r] < ld) { ld = dB[r]; lj = j; }
                    }
                }
            }
        }
    }
}

// ---------------------------------------------------------------- EdgeConv v2: parallel over (k, h)
template<int CIN, int COUT, bool BF16OUT>
__global__ __launch_bounds__(256) void edgeconv_kernel(
        const float* __restrict__ xin, const u16* __restrict__ knn,
        const float* __restrict__ w1, const float* __restrict__ b1,
        const float* __restrict__ w2, const float* __restrict__ b2,
        void* __restrict__ out) {
    const int bn = blockIdx.x;
    const int b = bn >> 11;
    const int tid = threadIdx.x;
    constexpr int SPLIT = 256 / COUT;
    constexpr int KPS = KK / SPLIT;
    __shared__ bf16 w1s[2 * CIN * 64];
    __shared__ bf16 w2s[64 * COUT];
    __shared__ float b1s[64], xi_s[CIN], base1[64];
    __shared__ float ediff[KK][CIN];
    __shared__ float h1s[KK][64];
    __shared__ float pm[SPLIT][COUT];
    __shared__ int js[KK];

    for (int p = tid; p < 2 * CIN * 64; p += 256) w1s[p] = __float2bfloat16(w1[p]);
    for (int p = tid; p < 64 * COUT; p += 256)    w2s[p] = __float2bfloat16(w2[p]);
    if (tid < 64) b1s[tid] = b1[tid];
    if (tid < CIN) xi_s[tid] = xin[(size_t)bn * CIN + tid];
    if (tid >= 64 && tid < 64 + KK) {
        int j = knn[bn * KK + (tid - 64)];
        js[tid - 64] = (j < NN) ? j : 0;
    }
    __syncthreads();

    for (int p = tid; p < KK * CIN; p += 256) {
        int k = p / CIN, c = p % CIN;
        ediff[k][c] = xin[((size_t)(b * NN + js[k])) * CIN + c] - xi_s[c];
    }
    if (tid < 64) {
        float a = b1s[tid];
        for (int c = 0; c < CIN; ++c) a += xi_s[c] * b2f(w1s[c * 64 + tid]);
        base1[tid] = a;
    }
    __syncthreads();

    for (int p = tid; p < KK * 64; p += 256) {
        int k = p >> 6, h = p & 63;
        float a = base1[h];
        for (int c = 0; c < CIN; ++c) a += ediff[k][c] * b2f(w1s[(CIN + c) * 64 + h]);
        h1s[k][h] = fmaxf(a, 0.f);
    }
    __syncthreads();

    {
        int o = tid % COUT, sp = tid / COUT;
        float mx = -INFINITY;
        for (int kk2 = 0; kk2 < KPS; ++kk2) {
            int k = sp * KPS + kk2;
            float a = 0.f;
            for (int c = 0; c < 64; ++c) a += h1s[k][c] * b2f(w2s[c * COUT + o]);
            mx = fmaxf(mx, a);
        }
        pm[sp][o] = mx;
    }
    __syncthreads();
    if (tid < COUT) {
        float mx = pm[0][tid];
        #pragma unroll
        for (int s2 = 1; s2 < SPLIT; ++s2) mx = fmaxf(mx, pm[s2][tid]);
        mx += b2[tid];
        if (BF16OUT) ((bf16*)out)[(size_t)bn * COUT + tid] = __float2bfloat16(mx);
        else         ((float*)out)[(size_t)bn * COUT + tid] = mx;
    }
}

// ---------------------------------------------------------------- global max over N (2-stage)
__global__ __launch_bounds__(128) void gmax1_kernel(const bf16* __restrict__ f2,
                                                    float* __restrict__ pmax) {
    const int b = blockIdx.x >> 4, ch = blockIdx.x & 15, c = threadIdx.x;
    float m = -INFINITY;
    const bf16* base = f2 + ((size_t)(b * NN + ch * 128)) * 128 + c;
    for (int n = 0; n < 128; ++n) m = fmaxf(m, b2f(base[(size_t)n * 128]));
    pmax[blockIdx.x * 128 + c] = m;
}

__global__ __launch_bounds__(128) void gmax2_kernel(const float* __restrict__ pmax,
                                                    float* __restrict__ glob) {
    const int b = blockIdx.x, c = threadIdx.x;
    float m = -INFINITY;
    for (int ch = 0; ch < 16; ++ch) m = fmaxf(m, pmax[(b * 16 + ch) * 128 + c]);
    glob[b * 128 + c] = m;
}

// ---------------------------------------------------------------- K + V^T for all heads (Path A)
__global__ __launch_bounds__(256) void kvt_kernel(const bf16* __restrict__ f2,
                                                  const float* __restrict__ qkv_w,
                                                  bf16* __restrict__ kk,
                                                  bf16* __restrict__ vt) {
    const int blk = blockIdx.x;
    const int h = blk >> 12;
    const int rg = blk & 4095;
    const int bn0 = rg * 4;
    const int b = bn0 >> 11, n0 = bn0 & 2047;
    const int tid = threadIdx.x;
    __shared__ float Ws[2][128][32];
    __shared__ float f2s[4][128];
    __shared__ float vbuf[4][32];
    for (int p = tid; p < 2 * 128 * 32; p += 256) {
        int kv = p >> 12, c = (p >> 5) & 127, d = p & 31;
        Ws[kv][c][d] = qkv_w[c * 384 + 128 + kv * 128 + h * 32 + d];
    }
    for (int p = tid; p < 4 * 128; p += 256) {
        int rr = p >> 7, c = p & 127;
        f2s[rr][c] = b2f(f2[(size_t)(bn0 + rr) * 128 + c]);
    }
    __syncthreads();
    const int rr = tid >> 6, u = tid & 63, kv = u >> 5, d = u & 31;
    float acc = 0.f;
    for (int c = 0; c < 128; ++c) acc += f2s[rr][c] * Ws[kv][c][d];
    if (kv == 0)
        kk[((size_t)(b * 4 + h) * 2048 + n0 + rr) * 32 + d] = __float2bfloat16(acc);
    else
        vbuf[rr][d] = acc;
    __syncthreads();
    if (tid < 128) {
        int dd = tid >> 2, r2 = tid & 3;
        vt[((size_t)(b * 4 + h) * 32 + dd) * 2048 + n0 + r2] = __float2bfloat16(vbuf[r2][dd]);
    }
}

// ---------------------------------------------------------------- MFMA flash attention (Path A)
__global__ __launch_bounds__(256) void attn_mfma_kernel(
        const bf16* __restrict__ f2, const float* __restrict__ qkv_w,
        const bf16* __restrict__ kk, const bf16* __restrict__ vt,
        bf16* __restrict__ atth) {
    const int blk = blockIdx.x;
    const int tile = blk & 31;
    const int h = (blk >> 5) & 3;
    const int b = blk >> 7;
    const int tid = threadIdx.x;
    const int w = tid >> 6;
    const int lane = tid & 63;
    const int lq = lane & 15;
    const int quad = lane >> 4;
    const float scale = 0.17677669529663687f;

    __shared__ __align__(16) bf16 WqT[32][128];
    __shared__ __align__(16) bf16 pbuf[4][2][16][32];

    for (int p = tid; p < 4096; p += 256) {
        int c = p >> 5, d = p & 31;
        WqT[d][c] = __float2bfloat16(qkv_w[c * 384 + h * 32 + d]);
    }
    __syncthreads();

    const int q0 = tile * 64 + w * 16;
    const bf16* fbase = f2 + ((size_t)(b * NN + q0 + lq)) * 128;
    f32x4 qc0 = {0.f, 0.f, 0.f, 0.f}, qc1 = {0.f, 0.f, 0.f, 0.f};
    #pragma unroll
    for (int kc = 0; kc < 4; ++kc) {
        short8 af = *(const short8*)(fbase + kc * 32 + quad * 8);
        short8 b0 = *(const short8*)(&WqT[lq][kc * 32 + quad * 8]);
        short8 b1 = *(const short8*)(&WqT[16 + lq][kc * 32 + quad * 8]);
        qc0 = __builtin_amdgcn_mfma_f32_16x16x32_bf16(af, b0, qc0, 0, 0, 0);
        qc1 = __builtin_amdgcn_mfma_f32_16x16x32_bf16(af, b1, qc1, 0, 0, 0);
    }
    {
        bf16* pw = &pbuf[w][0][0][0];
        #pragma unroll
        for (int r = 0; r < 4; ++r) {
            int qq = quad * 4 + r;
            pw[qq * 32 + lq]      = __float2bfloat16(qc0[r] * scale);
            pw[qq * 32 + 16 + lq] = __float2bfloat16(qc1[r] * scale);
        }
    }
    __syncthreads();
    const short8 qfrag = *(const short8*)(&pbuf[w][0][lq][quad * 8]);
    __syncthreads();

    const bf16* kb = kk + (size_t)(b * 4 + h) * 2048 * 32;
    const bf16* vb = vt + (size_t)(b * 4 + h) * 32 * 2048;
    f32x4 o0 = {0.f, 0.f, 0.f, 0.f}, o1 = {0.f, 0.f, 0.f, 0.f};
    f32x4 lsum = {0.f, 0.f, 0.f, 0.f};
    const short8 ones = {(short)0x3F80, (short)0x3F80, (short)0x3F80, (short)0x3F80,
                         (short)0x3F80, (short)0x3F80, (short)0x3F80, (short)0x3F80};

    for (int ch = 0; ch < 64; ++ch) {
        const int j0 = ch * 32;
        short8 kf0 = *(const short8*)(kb + (size_t)(j0 + lq) * 32 + quad * 8);
        short8 kf1 = *(const short8*)(kb + (size_t)(j0 + 16 + lq) * 32 + quad * 8);
        f32x4 z = {0.f, 0.f, 0.f, 0.f};
        f32x4 s0 = __builtin_amdgcn_mfma_f32_16x16x32_bf16(qfrag, kf0, z, 0, 0, 0);
        f32x4 s1 = __builtin_amdgcn_mfma_f32_16x16x32_bf16(qfrag, kf1, z, 0, 0, 0);
        bf16* pw = &pbuf[w][ch & 1][0][0];
        #pragma unroll
        for (int r = 0; r < 4; ++r) {
            int qq = quad * 4 + r;
            pw[qq * 32 + lq]      = __float2bfloat16(__expf(s0[r]));
            pw[qq * 32 + 16 + lq] = __float2bfloat16(__expf(s1[r]));
        }
        __syncthreads();
        short8 pf = *(const short8*)(pw + lq * 32 + quad * 8);
        short8 vf0 = *(const short8*)(vb + (size_t)lq * 2048 + j0 + quad * 8);
        short8 vf1 = *(const short8*)(vb + (size_t)(16 + lq) * 2048 + j0 + quad * 8);
        o0   = __builtin_amdgcn_mfma_f32_16x16x32_bf16(pf, vf0, o0, 0, 0, 0);
        o1   = __builtin_amdgcn_mfma_f32_16x16x32_bf16(pf, vf1, o1, 0, 0, 0);
        lsum = __builtin_amdgcn_mfma_f32_16x16x32_bf16(pf, ones, lsum, 0, 0, 0);
    }

    #pragma unroll
    for (int r = 0; r < 4; ++r) {
        int row = q0 + quad * 4 + r;
        float inv = 1.f / lsum[r];
        bf16* orow = atth + ((size_t)(b * NN + row)) * 128 + h * 32;
        orow[lq]      = __float2bfloat16(o0[r] * inv);
        orow[16 + lq] = __float2bfloat16(o1[r] * inv);
    }
}

// ---------------------------------------------------------------- K_h, V_h per head (Path B fallback)
__global__ __launch_bounds__(256) void kvh_kernel(const bf16* __restrict__ f2,
                                                  const float* __restrict__ qkv_w,
                                                  bf16* __restrict__ kk,
                                                  bf16* __restrict__ vv,
                                                  int h, int ostride) {
    const int bn0 = blockIdx.x * 4;
    const int tid = threadIdx.x;
    __shared__ float Ws[2][128][32];
    __shared__ float f2s[4][128];
    for (int p = tid; p < 2 * 128 * 32; p += 256) {
        int kv = p >> 12, c = (p >> 5) & 127, d = p & 31;
        Ws[kv][c][d] = qkv_w[c * 384 + 128 + kv * 128 + h * 32 + d];
    }
    for (int p = tid; p < 4 * 128; p += 256) {
        int rr = p >> 7, c = p & 127;
        f2s[rr][c] = b2f(f2[(size_t)(bn0 + rr) * 128 + c]);
    }
    __syncthreads();
    const int rr = tid >> 6, u = tid & 63, kv = u >> 5, d = u & 31;
    float acc = 0.f;
    for (int c = 0; c < 128; ++c) acc += f2s[rr][c] * Ws[kv][c][d];
    bf16* dst = kv ? vv : kk;
    dst[(size_t)(bn0 + rr) * ostride + d] = __float2bfloat16(acc);
}

// ---------------------------------------------------------------- VALU attention (Path B fallback)
__global__ __launch_bounds__(256) void attnh_kernel(const bf16* __restrict__ f2,
                                                    const float* __restrict__ qkv_w,
                                                    const bf16* __restrict__ kk,
                                                    const bf16* __restrict__ vv,
                                                    bf16* __restrict__ atth,
                                                    int h_in, int kstride) {
    int blk = blockIdx.x;
    int h;
    if (h_in < 0) { h = blk >> 8; blk &= 255; } else { h = h_in; }
    const int tile = blk & 31;
    const int b = blk >> 5;
    const int tid = threadIdx.x;
    const int r = tid & 63;
    const int sp = tid >> 6;
    const int i = tile * 64 + r;
    const float scale = 0.17677669529663687f;
    __shared__ float WqS[128 * 32];
    __shared__ float mred[4][64], lred[4][64];
    __shared__ float accs[4][64][32];

    for (int p = tid; p < 4096; p += 256) {
        int c = p >> 5, d = p & 31;
        WqS[p] = qkv_w[c * 384 + h * 32 + d];
    }
    __syncthreads();

    float q[32];
    #pragma unroll
    for (int d = 0; d < 32; ++d) q[d] = 0.f;
    const bf16* frow = f2 + (size_t)(b * NN + i) * 128;
    for (int cc = 0; cc < 16; ++cc) {
        float fv[8];
        load_bf16x8(frow + cc * 8, fv);
        #pragma unroll
        for (int u2 = 0; u2 < 8; ++u2) {
            const float* wrow = &WqS[(cc * 8 + u2) * 32];
            #pragma unroll
            for (int d = 0; d < 32; ++d) q[d] += fv[u2] * wrow[d];
        }
    }

    const int hoff = (kstride == 128) ? h * 32 : 0;
    const bf16* kb = kk + (size_t)b * NN * kstride + hoff;
    const bf16* vb = vv + (size_t)b * NN * kstride + hoff;
    const int j0 = sp * 512, j1 = j0 + 512;

    float m = -INFINITY;
    for (int j = j0; j < j1; ++j) {
        const bf16* kr = kb + (size_t)j * kstride;
        float dsum = 0.f;
        #pragma unroll
        for (int d = 0; d < 32; ++d) dsum += q[d] * b2f(kr[d]);
        m = fmaxf(m, dsum * scale);
    }
    mred[sp][r] = m;
    __syncthreads();
    m = fmaxf(fmaxf(mred[0][r], mred[1][r]), fmaxf(mred[2][r], mred[3][r]));

    float l = 0.f;
    float a[32];
    #pragma unroll
    for (int d = 0; d < 32; ++d) a[d] = 0.f;
    for (int j = j0; j < j1; ++j) {
        const bf16* kr = kb + (size_t)j * kstride;
        float dsum = 0.f;
        #pragma unroll
        for (int d = 0; d < 32; ++d) dsum += q[d] * b2f(kr[d]);
        float p = __expf(dsum * scale - m);
        l += p;
        const bf16* vr = vb + (size_t)j * kstride;
        #pragma unroll
        for (int d = 0; d < 32; ++d) a[d] += p * b2f(vr[d]);
    }
    lred[sp][r] = l;
    #pragma unroll
    for (int d = 0; d < 32; ++d) accs[sp][r][d] = a[d];
    __syncthreads();

    const int row = tid >> 2;
    const int dbase = (tid & 3) * 8;
    const float denom = lred[0][row] + lred[1][row] + lred[2][row] + lred[3][row];
    bf16* orow = atth + (size_t)(b * NN + tile * 64 + row) * 128 + h * 32;
    #pragma unroll
    for (int uu = 0; uu < 8; ++uu) {
        int d = dbase + uu;
        float v = accs[0][row][d] + accs[1][row][d] + accs[2][row][d] + accs[3][row][d];
        orow[d] = __float2bfloat16(v / denom);
    }
}

// ---------------------------------------------------------------- fused out-proj + concat + refine MLP + log_softmax
__global__ __launch_bounds__(128) void final_kernel(
        const bf16* __restrict__ f2, const float* __restrict__ glob,
        const bf16* __restrict__ atth,
        const float* __restrict__ out_w, const float* __restrict__ out_b,
        const float* __restrict__ r1_w, const float* __restrict__ r1_b,
        const float* __restrict__ r2_w, const float* __restrict__ r2_b,
        const float* __restrict__ r3_w, const float* __restrict__ r3_b,
        float* __restrict__ out) {
    const int bn0 = blockIdx.x * 4;
    const int b = bn0 >> 11;
    const int tid = threadIdx.x;
    __shared__ float attin[4][128], comb[4][384], h1[4][128], h2[4][64];
    __shared__ float logits[4][20], lse[4];

    #pragma unroll
    for (int rr = 0; rr < 4; ++rr) {
        attin[rr][tid]      = b2f(atth[(size_t)(bn0 + rr) * 128 + tid]);
        comb[rr][tid]       = b2f(f2[(size_t)(bn0 + rr) * 128 + tid]);
        comb[rr][128 + tid] = glob[b * 128 + tid];
    }
    __syncthreads();
    {
        float a0 = 0.f, a1 = 0.f, a2 = 0.f, a3 = 0.f;
        for (int c = 0; c < 128; ++c) {
            float wv = out_w[c * 128 + tid];
            a0 += attin[0][c] * wv; a1 += attin[1][c] * wv;
            a2 += attin[2][c] * wv; a3 += attin[3][c] * wv;
        }
        float bb = out_b[tid];
        comb[0][256 + tid] = a0 + bb; comb[1][256 + tid] = a1 + bb;
        comb[2][256 + tid] = a2 + bb; comb[3][256 + tid] = a3 + bb;
    }
    __syncthreads();
    {
        float a0 = 0.f, a1 = 0.f, a2 = 0.f, a3 = 0.f;
        for (int c = 0; c < 384; ++c) {
            float wv = r1_w[c * 128 + tid];
            a0 += comb[0][c] * wv; a1 += comb[1][c] * wv;
            a2 += comb[2][c] * wv; a3 += comb[3][c] * wv;
        }
        float bb = r1_b[tid];
        h1[0][tid] = fmaxf(a0 + bb, 0.f); h1[1][tid] = fmaxf(a1 + bb, 0.f);
        h1[2][tid] = fmaxf(a2 + bb, 0.f); h1[3][tid] = fmaxf(a3 + bb, 0.f);
    }
    __syncthreads();
    if (tid < 64) {
        float a0 = 0.f, a1 = 0.f, a2 = 0.f, a3 = 0.f;
        for (int c = 0; c < 128; ++c) {
            float wv = r2_w[c * 64 + tid];
            a0 += h1[0][c] * wv; a1 += h1[1][c] * wv;
            a2 += h1[2][c] * wv; a3 += h1[3][c] * wv;
        }
        float bb = r2_b[tid];
        h2[0][tid] = fmaxf(a0 + bb, 0.f); h2[1][tid] = fmaxf(a1 + bb, 0.f);
        h2[2][tid] = fmaxf(a2 + bb, 0.f); h2[3][tid] = fmaxf(a3 + bb, 0.f);
    }
    __syncthreads();
    if (tid < 20) {
        float a0 = 0.f, a1 = 0.f, a2 = 0.f, a3 = 0.f;
        for (int c = 0; c < 64; ++c) {
            float wv = r3_w[c * 20 + tid];
            a0 += h2[0][c] * wv; a1 += h2[1][c] * wv;
            a2 += h2[2][c] * wv; a3 += h2[3][c] * wv;
        }
        float bb = r3_b[tid];
        logits[0][tid] = a0 + bb; logits[1][tid] = a1 + bb;
        logits[2][tid] = a2 + bb; logits[3][tid] = a3 + bb;
    }
    __syncthreads();
    if (tid < 4) {
        float m = -INFINITY;
        for (int u = 0; u < 20; ++u) m = fmaxf(m, logits[tid][u]);
        float s = 0.f;
        for (int u = 0; u < 20; ++u) s += expf(logits[tid][u] - m);
        lse[tid] = m + logf(s);
    }
    __syncthreads();
    if (tid < 80) {
        int rr = tid / 20, cls = tid % 20;
        out[(size_t)(bn0 + rr) * 20 + cls] = logits[rr][cls] - lse[rr];
    }
}

// ----------------------------------------------------------------------------
extern "C" void kernel_launch(void* const* d_in, const int* in_sizes, int n_in,
                              void* d_out, int out_size, void* d_ws, size_t ws_size,
                              hipStream_t stream) {
    const float* x      = (const float*)d_in[0];
    const float* ec1_w1 = (const float*)d_in[2];
    const float* ec1_b1 = (const float*)d_in[3];
    const float* ec1_w2 = (const float*)d_in[4];
    const float* ec1_b2 = (const float*)d_in[5];
    const float* ec2_w1 = (const float*)d_in[6];
    const float* ec2_b1 = (const float*)d_in[7];
    const float* ec2_w2 = (const float*)d_in[8];
    const float* ec2_b2 = (const float*)d_in[9];
    const float* qkv_w  = (const float*)d_in[10];
    const float* out_w  = (const float*)d_in[11];
    const float* out_b  = (const float*)d_in[12];
    const float* r1_w   = (const float*)d_in[13];
    const float* r1_b   = (const float*)d_in[14];
    const float* r2_w   = (const float*)d_in[15];
    const float* r2_b   = (const float*)d_in[16];
    const float* r3_w   = (const float*)d_in[17];
    const float* r3_b   = (const float*)d_in[18];
    float* out = (float*)d_out;

    const size_t MB = 1024 * 1024;
    const size_t NEED_B = 10555392;
    const size_t NEED_A = 16 * MB + 65536 + 4096;
    if (ws_size < NEED_B) return;
    const bool bigws = (ws_size >= NEED_A);

    char* base = (char*)d_ws;
    bf16*  f2   = (bf16*)(base);
    float* f1T  = (float*)(base);
    float* sqb  = (float*)(base + 4 * MB);
    float* f1   = (float*)(base + 4 * MB + 65536);
    u16*   knn  = (u16*)(base + 8 * MB + 65536);
    float* xT3  = (float*)(base + 8 * MB + 65536 + 655360);

    sqT_kernel<3><<<BBNN / 256, 256, 0, stream>>>(x, sqb, xT3);
    knn_fast_kernel<3, 3><<<BB * 128, 512, 0, stream>>>(x, xT3, sqb, knn);
    edgeconv_kernel<3, 64, false><<<BB * NN, 256, 0, stream>>>(
        x, knn, ec1_w1, ec1_b1, ec1_w2, ec1_b2, f1);

    sqT_kernel<64><<<BBNN / 256, 256, 0, stream>>>(f1, sqb, f1T);
    knn_fast_kernel<64, 8><<<BB * 128, 512, 0, stream>>>(f1, f1T, sqb, knn);
    edgeconv_kernel<64, 128, true><<<BB * NN, 256, 0, stream>>>(
        f1, knn, ec2_w1, ec2_b1, ec2_w2, ec2_b2, f2);

    if (bigws) {
        bf16*  kkA  = (bf16*)(base + 4 * MB);
        bf16*  vtA  = (bf16*)(base + 8 * MB);
        bf16*  atth = (bf16*)(base + 12 * MB);
        float* pmax = (float*)(base + 16 * MB);
        float* glob = (float*)(base + 16 * MB + 65536);

        gmax1_kernel<<<BB * 16, 128, 0, stream>>>(f2, pmax);
        gmax2_kernel<<<BB, 128, 0, stream>>>(pmax, glob);

        kvt_kernel<<<4 * BB * NN / 4, 256, 0, stream>>>(f2, qkv_w, kkA, vtA);
        attn_mfma_kernel<<<BB * 4 * 32, 256, 0, stream>>>(f2, qkv_w, kkA, vtA, atth);

        final_kernel<<<BB * NN / 4, 128, 0, stream>>>(
            f2, glob, atth, out_w, out_b, r1_w, r1_b, r2_w, r2_b, r3_w, r3_b, out);
    } else {
        bf16*  kk   = (bf16*)(base + 4 * MB);
        bf16*  vv   = (bf16*)(base + 5 * MB);
        bf16*  atth = (bf16*)(base + 6 * MB);
        float* pmax = (float*)(base + 10 * MB);
        float* glob = (float*)(base + 10 * MB + 65536);

        gmax1_kernel<<<BB * 16, 128, 0, stream>>>(f2, pmax);
        gmax2_kernel<<<BB, 128, 0, stream>>>(pmax, glob);

        for (int h = 0; h < 4; ++h) {
            kvh_kernel<<<BB * NN / 4, 256, 0, stream>>>(f2, qkv_w, kk, vv, h, 32);
            attnh_kernel<<<BB * 32, 256, 0, stream>>>(f2, qkv_w, kk, vv, atth, h, 32);
        }

        final_kernel<<<BB * NN / 4, 128, 0, stream>>>(
            f2, glob, atth, out_w, out_b, r1_w, r1_b, r2_w, r2_b, r3_w, r3_b, out);
    }
}

// Round 12
// 919.709 us; speedup vs baseline: 7.1162x; 1.2449x over previous
//
#include <hip/hip_runtime.h>
#include <hip/hip_bf16.h>

#define BB 8
#define NN 2048
#define KK 20
#define BBNN (BB * NN)

typedef __hip_bfloat16 bf16;
typedef unsigned short u16;
typedef __attribute__((ext_vector_type(8))) short short8;
typedef __attribute__((ext_vector_type(4))) float f32x4;

__device__ __forceinline__ float b2f(bf16 v) { return __bfloat162float(v); }

// ---------------------------------------------------------------- sq + transpose (fused)
template<int C>
__global__ __launch_bounds__(256) void sqT_kernel(const float* __restrict__ xin,
                                                  float* __restrict__ sq,
                                                  float* __restrict__ xT) {
    int t = blockIdx.x * 256 + threadIdx.x;
    if (t >= BBNN) return;
    const float* p = xin + (size_t)t * C;
    float s = 0.f;
    for (int c = 0; c < C; ++c) {
        float v = p[c];
        s += v * v;
        xT[(size_t)c * BBNN + t] = v;
    }
    sq[t] = s;
}

// ---------------------------------------------------------------- fast kNN v4 (unchanged)
template<int C, int CH>
__global__ __launch_bounds__(512, 4) void knn_fast_kernel(
        const float* __restrict__ xrows,
        const float* __restrict__ xT,
        const float* __restrict__ sq,
        u16* __restrict__ idx_out) {
    __shared__ __align__(16) float xs[CH][256];
    const int blk = blockIdx.x;            // BB * 128
    const int b = blk >> 7;
    const int tile = blk & 127;
    const int w = threadIdx.x >> 6;
    const int s = threadIdx.x & 63;
    const int iA = tile * 16 + w * 2;
    const int bn0 = b * NN;
    constexpr int NCH = C / CH;

    float dA[32], dB[32];
    #pragma unroll
    for (int r = 0; r < 32; ++r) { dA[r] = 0.f; dB[r] = 0.f; }

    const int qbaseA = __builtin_amdgcn_readfirstlane((bn0 + iA) * C);
    for (int ch = 0; ch < NCH; ++ch) {
        float xqA[CH], xqB[CH];
        #pragma unroll
        for (int cc = 0; cc < CH; ++cc) {
            xqA[cc] = xrows[qbaseA + ch * CH + cc];
            xqB[cc] = xrows[qbaseA + C + ch * CH + cc];
        }
        #pragma unroll 1
        for (int t = 0; t < 8; ++t) {
            __syncthreads();
            for (int p = threadIdx.x; p < CH * 64; p += 512) {
                int c = p >> 6, j4 = (p & 63) << 2;
                *(float4*)&xs[c][j4] =
                    *(const float4*)(xT + (size_t)(ch * CH + c) * BBNN + bn0 + t * 256 + j4);
            }
            __syncthreads();
            float aA0 = 0.f, aA1 = 0.f, aA2 = 0.f, aA3 = 0.f;
            float aB0 = 0.f, aB1 = 0.f, aB2 = 0.f, aB3 = 0.f;
            #pragma unroll
            for (int cc = 0; cc < CH; ++cc) {
                float4 xv = *(const float4*)&xs[cc][s * 4];
                float qA = xqA[cc], qB = xqB[cc];
                aA0 += qA * xv.x; aA1 += qA * xv.y; aA2 += qA * xv.z; aA3 += qA * xv.w;
                aB0 += qB * xv.x; aB1 += qB * xv.y; aB2 += qB * xv.z; aB3 += qB * xv.w;
            }
            dA[t * 4 + 0] += aA0; dA[t * 4 + 1] += aA1;
            dA[t * 4 + 2] += aA2; dA[t * 4 + 3] += aA3;
            dB[t * 4 + 0] += aB0; dB[t * 4 + 1] += aB1;
            dB[t * 4 + 2] += aB2; dB[t * 4 + 3] += aB3;
        }
    }
    const float sqiA = sq[bn0 + iA];
    const float sqiB = sq[bn0 + iA + 1];
    #pragma unroll
    for (int r = 0; r < 32; ++r) {
        int j = ((r >> 2) << 8) + (s << 2) + (r & 3);
        float sqj = sq[bn0 + j];
        dA[r] = (sqiA + sqj) - 2.f * dA[r];
        dB[r] = (sqiB + sqj) - 2.f * dB[r];
    }

    {
        float ld = INFINITY; int lj = 0x7fffffff;
        #pragma unroll
        for (int r = 0; r < 32; ++r) {
            int j = ((r >> 2) << 8) + (s << 2) + (r & 3);
            if (dA[r] < ld) { ld = dA[r]; lj = j; }
        }
        for (int k = 0; k < KK; ++k) {
            float rd = ld; int rj = lj;
            #pragma unroll
            for (int m = 1; m < 64; m <<= 1) {
                float od = __shfl_xor(rd, m);
                int   oj = __shfl_xor(rj, m);
                if (od < rd || (od == rd && oj < rj)) { rd = od; rj = oj; }
            }
            if (s == 0) idx_out[(size_t)(bn0 + iA) * KK + k] = (u16)rj;
            if (k + 1 < KK) {
                if (s == ((rj & 255) >> 2)) {
                    int rr = ((rj >> 8) << 2) + (rj & 3);
                    ld = INFINITY; lj = 0x7fffffff;
                    #pragma unroll
                    for (int r = 0; r < 32; ++r) {
                        if (r == rr) dA[r] = INFINITY;
                        int j = ((r >> 2) << 8) + (s << 2) + (r & 3);
                        if (dA[r] < ld) { ld = dA[r]; lj = j; }
                    }
                }
            }
        }
    }
    {
        float ld = INFINITY; int lj = 0x7fffffff;
        #pragma unroll
        for (int r = 0; r < 32; ++r) {
            int j = ((r >> 2) << 8) + (s << 2) + (r & 3);
            if (dB[r] < ld) { ld = dB[r]; lj = j; }
        }
        for (int k = 0; k < KK; ++k) {
            float rd = ld; int rj = lj;
            #pragma unroll
            for (int m = 1; m < 64; m <<= 1) {
                float od = __shfl_xor(rd, m);
                int   oj = __shfl_xor(rj, m);
                if (od < rd || (od == rd && oj < rj)) { rd = od; rj = oj; }
            }
            if (s == 0) idx_out[(size_t)(bn0 + iA + 1) * KK + k] = (u16)rj;
            if (k + 1 < KK) {
                if (s == ((rj & 255) >> 2)) {
                    int rr = ((rj >> 8) << 2) + (rj & 3);
                    ld = INFINITY; lj = 0x7fffffff;
                    #pragma unroll
                    for (int r = 0; r < 32; ++r) {
                        if (r == rr) dB[r] = INFINITY;
                        int j = ((r >> 2) << 8) + (s << 2) + (r & 3);
                        if (dB[r] < ld) { ld = dB[r]; lj = j; }
                    }
                }
            }
        }
    }
}

// ---------------------------------------------------------------- G[n][h] = x[n] . w1_lower[.][h]
// w1 row-major [2*CIN][64]; lower half = rows CIN..2CIN-1 (the (xj-xi) part).
template<int CIN>
__global__ __launch_bounds__(256) void gemmG_kernel(const float* __restrict__ xin,
                                                    const float* __restrict__ w1,
                                                    float* __restrict__ G) {
    __shared__ float wls[CIN * 64];
    __shared__ float xr[4][CIN];
    const int bn0 = blockIdx.x * 4;
    const int tid = threadIdx.x;
    for (int p = tid; p < CIN * 64; p += 256) wls[p] = w1[CIN * 64 + p];
    for (int p = tid; p < 4 * CIN; p += 256)
        xr[p / CIN][p % CIN] = xin[(size_t)bn0 * CIN + p];
    __syncthreads();
    const int pp = tid >> 6, h = tid & 63;
    float a = 0.f;
    for (int c = 0; c < CIN; ++c) a += xr[pp][c] * wls[c * 64 + h];
    G[(size_t)(bn0 + pp) * 64 + h] = a;
}

// ---------------------------------------------------------------- EdgeConv v3: G-decomposed
// 4 points/block. Layer1 per edge = gather G[j] + add (no MACs):
//   h1[k][h] = relu( (b1[h] + xi.W1u[h] - G[i][h]) + G[j][h] )   [algebraically
//   identical to relu(b1 + xi.W1u + (xj-xi).W1l); fp reorder only]
// Layer2: thread owns output column o; W2 column held in 64 VGPRs (loaded once
// from global, L2-resident) -> pure v_fmac_f32 with h1 float4 LDS broadcasts.
template<int CIN, int COUT, bool BF16OUT>
__global__ __launch_bounds__(256) void edgeconv3_kernel(
        const float* __restrict__ xin, const u16* __restrict__ knn,
        const float* __restrict__ w1, const float* __restrict__ b1,
        const float* __restrict__ w2, const float* __restrict__ b2,
        const float* __restrict__ G, void* __restrict__ out) {
    constexpr int SPLIT = 256 / COUT;      // 2 for COUT=128, 4 for COUT=64
    constexpr int KPS = KK / SPLIT;        // 10 / 5
    const int bn0 = blockIdx.x * 4;
    const int b = bn0 >> 11;
    const int tid = threadIdx.x;
    __shared__ float w1us[CIN * 64];                   // upper half (xi part)
    __shared__ float xr[4][CIN];
    __shared__ __align__(16) float h1s[4][KK][64];
    __shared__ float pms[4][SPLIT][COUT];
    __shared__ int js[4][KK];

    for (int p = tid; p < CIN * 64; p += 256) w1us[p] = w1[p];
    for (int p = tid; p < 4 * CIN; p += 256)
        xr[p / CIN][p % CIN] = xin[(size_t)bn0 * CIN + p];
    if (tid < 4 * KK) {
        int j = knn[(size_t)(bn0 + tid / KK) * KK + (tid % KK)];
        js[tid / KK][tid % KK] = (j < NN) ? j : 0;
    }
    __syncthreads();

    // phase 1: h1[pp][k][h]
    {
        const int pp = tid >> 6, h = tid & 63;
        float u = b1[h];
        for (int c = 0; c < CIN; ++c) u += xr[pp][c] * w1us[c * 64 + h];
        u -= G[(size_t)(bn0 + pp) * 64 + h];
        const float* Gb = G + (size_t)b * NN * 64 + h;
        for (int k = 0; k < KK; ++k) {
            float gj = Gb[(size_t)js[pp][k] * 64];
            h1s[pp][k][h] = fmaxf(u + gj, 0.f);
        }
    }
    __syncthreads();

    // phase 2: layer2, W2 column in registers
    {
        const int o = tid % COUT, ks = tid / COUT;
        float wcol[64];
        #pragma unroll
        for (int c = 0; c < 64; ++c) wcol[c] = w2[c * COUT + o];
        #pragma unroll
        for (int pp = 0; pp < 4; ++pp) {
            float mx = -INFINITY;
            for (int k = ks * KPS; k < (ks + 1) * KPS; ++k) {
                float acc = 0.f;
                #pragma unroll
                for (int c4 = 0; c4 < 16; ++c4) {
                    float4 hv = *(const float4*)&h1s[pp][k][c4 * 4];
                    acc += hv.x * wcol[c4 * 4 + 0];
                    acc += hv.y * wcol[c4 * 4 + 1];
                    acc += hv.z * wcol[c4 * 4 + 2];
                    acc += hv.w * wcol[c4 * 4 + 3];
                }
                mx = fmaxf(mx, acc);
            }
            pms[pp][ks][o] = mx;
        }
    }
    __syncthreads();
    for (int idx = tid; idx < 4 * COUT; idx += 256) {
        int pp = idx / COUT, oo = idx % COUT;
        float mx = pms[pp][0][oo];
        #pragma unroll
        for (int s2 = 1; s2 < SPLIT; ++s2) mx = fmaxf(mx, pms[pp][s2][oo]);
        mx += b2[oo];
        if (BF16OUT) ((bf16*)out)[(size_t)(bn0 + pp) * COUT + oo] = __float2bfloat16(mx);
        else         ((float*)out)[(size_t)(bn0 + pp) * COUT + oo] = mx;
    }
}

// ---------------------------------------------------------------- global max over N (2-stage)
__global__ __launch_bounds__(128) void gmax1_kernel(const bf16* __restrict__ f2,
                                                    float* __restrict__ pmax) {
    const int b = blockIdx.x >> 4, ch = blockIdx.x & 15, c = threadIdx.x;
    float m = -INFINITY;
    const bf16* base = f2 + ((size_t)(b * NN + ch * 128)) * 128 + c;
    for (int n = 0; n < 128; ++n) m = fmaxf(m, b2f(base[(size_t)n * 128]));
    pmax[blockIdx.x * 128 + c] = m;
}

__global__ __launch_bounds__(128) void gmax2_kernel(const float* __restrict__ pmax,
                                                    float* __restrict__ glob) {
    const int b = blockIdx.x, c = threadIdx.x;
    float m = -INFINITY;
    for (int ch = 0; ch < 16; ++ch) m = fmaxf(m, pmax[(b * 16 + ch) * 128 + c]);
    glob[b * 128 + c] = m;
}

// ---------------------------------------------------------------- K + V^T for all heads
__global__ __launch_bounds__(256) void kvt_kernel(const bf16* __restrict__ f2,
                                                  const float* __restrict__ qkv_w,
                                                  bf16* __restrict__ kk,
                                                  bf16* __restrict__ vt) {
    const int blk = blockIdx.x;
    const int h = blk >> 12;
    const int rg = blk & 4095;
    const int bn0 = rg * 4;
    const int b = bn0 >> 11, n0 = bn0 & 2047;
    const int tid = threadIdx.x;
    __shared__ float Ws[2][128][32];
    __shared__ float f2s[4][128];
    __shared__ float vbuf[4][32];
    for (int p = tid; p < 2 * 128 * 32; p += 256) {
        int kv = p >> 12, c = (p >> 5) & 127, d = p & 31;
        Ws[kv][c][d] = qkv_w[c * 384 + 128 + kv * 128 + h * 32 + d];
    }
    for (int p = tid; p < 4 * 128; p += 256) {
        int rr = p >> 7, c = p & 127;
        f2s[rr][c] = b2f(f2[(size_t)(bn0 + rr) * 128 + c]);
    }
    __syncthreads();
    const int rr = tid >> 6, u = tid & 63, kv = u >> 5, d = u & 31;
    float acc = 0.f;
    for (int c = 0; c < 128; ++c) acc += f2s[rr][c] * Ws[kv][c][d];
    if (kv == 0)
        kk[((size_t)(b * 4 + h) * 2048 + n0 + rr) * 32 + d] = __float2bfloat16(acc);
    else
        vbuf[rr][d] = acc;
    __syncthreads();
    if (tid < 128) {
        int dd = tid >> 2, r2 = tid & 3;
        vt[((size_t)(b * 4 + h) * 32 + dd) * 2048 + n0 + r2] = __float2bfloat16(vbuf[r2][dd]);
    }
}

// ---------------------------------------------------------------- MFMA flash attention
__global__ __launch_bounds__(256) void attn_mfma_kernel(
        const bf16* __restrict__ f2, const float* __restrict__ qkv_w,
        const bf16* __restrict__ kk, const bf16* __restrict__ vt,
        bf16* __restrict__ atth) {
    const int blk = blockIdx.x;
    const int tile = blk & 31;
    const int h = (blk >> 5) & 3;
    const int b = blk >> 7;
    const int tid = threadIdx.x;
    const int w = tid >> 6;
    const int lane = tid & 63;
    const int lq = lane & 15;
    const int quad = lane >> 4;
    const float scale = 0.17677669529663687f;

    __shared__ __align__(16) bf16 WqT[32][128];
    __shared__ __align__(16) bf16 pbuf[4][2][16][32];

    for (int p = tid; p < 4096; p += 256) {
        int c = p >> 5, d = p & 31;
        WqT[d][c] = __float2bfloat16(qkv_w[c * 384 + h * 32 + d]);
    }
    __syncthreads();

    const int q0 = tile * 64 + w * 16;
    const bf16* fbase = f2 + ((size_t)(b * NN + q0 + lq)) * 128;
    f32x4 qc0 = {0.f, 0.f, 0.f, 0.f}, qc1 = {0.f, 0.f, 0.f, 0.f};
    #pragma unroll
    for (int kc = 0; kc < 4; ++kc) {
        short8 af = *(const short8*)(fbase + kc * 32 + quad * 8);
        short8 b0 = *(const short8*)(&WqT[lq][kc * 32 + quad * 8]);
        short8 b1 = *(const short8*)(&WqT[16 + lq][kc * 32 + quad * 8]);
        qc0 = __builtin_amdgcn_mfma_f32_16x16x32_bf16(af, b0, qc0, 0, 0, 0);
        qc1 = __builtin_amdgcn_mfma_f32_16x16x32_bf16(af, b1, qc1, 0, 0, 0);
    }
    {
        bf16* pw = &pbuf[w][0][0][0];
        #pragma unroll
        for (int r = 0; r < 4; ++r) {
            int qq = quad * 4 + r;
            pw[qq * 32 + lq]      = __float2bfloat16(qc0[r] * scale);
            pw[qq * 32 + 16 + lq] = __float2bfloat16(qc1[r] * scale);
        }
    }
    __syncthreads();
    const short8 qfrag = *(const short8*)(&pbuf[w][0][lq][quad * 8]);
    __syncthreads();

    const bf16* kb = kk + (size_t)(b * 4 + h) * 2048 * 32;
    const bf16* vb = vt + (size_t)(b * 4 + h) * 32 * 2048;
    f32x4 o0 = {0.f, 0.f, 0.f, 0.f}, o1 = {0.f, 0.f, 0.f, 0.f};
    f32x4 lsum = {0.f, 0.f, 0.f, 0.f};
    const short8 ones = {(short)0x3F80, (short)0x3F80, (short)0x3F80, (short)0x3F80,
                         (short)0x3F80, (short)0x3F80, (short)0x3F80, (short)0x3F80};

    for (int ch = 0; ch < 64; ++ch) {
        const int j0 = ch * 32;
        short8 kf0 = *(const short8*)(kb + (size_t)(j0 + lq) * 32 + quad * 8);
        short8 kf1 = *(const short8*)(kb + (size_t)(j0 + 16 + lq) * 32 + quad * 8);
        f32x4 z = {0.f, 0.f, 0.f, 0.f};
        f32x4 s0 = __builtin_amdgcn_mfma_f32_16x16x32_bf16(qfrag, kf0, z, 0, 0, 0);
        f32x4 s1 = __builtin_amdgcn_mfma_f32_16x16x32_bf16(qfrag, kf1, z, 0, 0, 0);
        bf16* pw = &pbuf[w][ch & 1][0][0];
        #pragma unroll
        for (int r = 0; r < 4; ++r) {
            int qq = quad * 4 + r;
            pw[qq * 32 + lq]      = __float2bfloat16(__expf(s0[r]));
            pw[qq * 32 + 16 + lq] = __float2bfloat16(__expf(s1[r]));
        }
        __syncthreads();
        short8 pf = *(const short8*)(pw + lq * 32 + quad * 8);
        short8 vf0 = *(const short8*)(vb + (size_t)lq * 2048 + j0 + quad * 8);
        short8 vf1 = *(const short8*)(vb + (size_t)(16 + lq) * 2048 + j0 + quad * 8);
        o0   = __builtin_amdgcn_mfma_f32_16x16x32_bf16(pf, vf0, o0, 0, 0, 0);
        o1   = __builtin_amdgcn_mfma_f32_16x16x32_bf16(pf, vf1, o1, 0, 0, 0);
        lsum = __builtin_amdgcn_mfma_f32_16x16x32_bf16(pf, ones, lsum, 0, 0, 0);
    }

    #pragma unroll
    for (int r = 0; r < 4; ++r) {
        int row = q0 + quad * 4 + r;
        float inv = 1.f / lsum[r];
        bf16* orow = atth + ((size_t)(b * NN + row)) * 128 + h * 32;
        orow[lq]      = __float2bfloat16(o0[r] * inv);
        orow[16 + lq] = __float2bfloat16(o1[r] * inv);
    }
}

// ---------------------------------------------------------------- fused out-proj + concat + refine MLP + log_softmax
__global__ __launch_bounds__(128) void final_kernel(
        const bf16* __restrict__ f2, const float* __restrict__ glob,
        const bf16* __restrict__ atth,
        const float* __restrict__ out_w, const float* __restrict__ out_b,
        const float* __restrict__ r1_w, const float* __restrict__ r1_b,
        const float* __restrict__ r2_w, const float* __restrict__ r2_b,
        const float* __restrict__ r3_w, const float* __restrict__ r3_b,
        float* __restrict__ out) {
    const int bn0 = blockIdx.x * 4;
    const int b = bn0 >> 11;
    const int tid = threadIdx.x;
    __shared__ float attin[4][128], comb[4][384], h1[4][128], h2[4][64];
    __shared__ float logits[4][20], lse[4];

    #pragma unroll
    for (int rr = 0; rr < 4; ++rr) {
        attin[rr][tid]      = b2f(atth[(size_t)(bn0 + rr) * 128 + tid]);
        comb[rr][tid]       = b2f(f2[(size_t)(bn0 + rr) * 128 + tid]);
        comb[rr][128 + tid] = glob[b * 128 + tid];
    }
    __syncthreads();
    {
        float a0 = 0.f, a1 = 0.f, a2 = 0.f, a3 = 0.f;
        for (int c = 0; c < 128; ++c) {
            float wv = out_w[c * 128 + tid];
            a0 += attin[0][c] * wv; a1 += attin[1][c] * wv;
            a2 += attin[2][c] * wv; a3 += attin[3][c] * wv;
        }
        float bb = out_b[tid];
        comb[0][256 + tid] = a0 + bb; comb[1][256 + tid] = a1 + bb;
        comb[2][256 + tid] = a2 + bb; comb[3][256 + tid] = a3 + bb;
    }
    __syncthreads();
    {
        float a0 = 0.f, a1 = 0.f, a2 = 0.f, a3 = 0.f;
        for (int c = 0; c < 384; ++c) {
            float wv = r1_w[c * 128 + tid];
            a0 += comb[0][c] * wv; a1 += comb[1][c] * wv;
            a2 += comb[2][c] * wv; a3 += comb[3][c] * wv;
        }
        float bb = r1_b[tid];
        h1[0][tid] = fmaxf(a0 + bb, 0.f); h1[1][tid] = fmaxf(a1 + bb, 0.f);
        h1[2][tid] = fmaxf(a2 + bb, 0.f); h1[3][tid] = fmaxf(a3 + bb, 0.f);
    }
    __syncthreads();
    if (tid < 64) {
        float a0 = 0.f, a1 = 0.f, a2 = 0.f, a3 = 0.f;
        for (int c = 0; c < 128; ++c) {
            float wv = r2_w[c * 64 + tid];
            a0 += h1[0][c] * wv; a1 += h1[1][c] * wv;
            a2 += h1[2][c] * wv; a3 += h1[3][c] * wv;
        }
        float bb = r2_b[tid];
        h2[0][tid] = fmaxf(a0 + bb, 0.f); h2[1][tid] = fmaxf(a1 + bb, 0.f);
        h2[2][tid] = fmaxf(a2 + bb, 0.f); h2[3][tid] = fmaxf(a3 + bb, 0.f);
    }
    __syncthreads();
    if (tid < 20) {
        float a0 = 0.f, a1 = 0.f, a2 = 0.f, a3 = 0.f;
        for (int c = 0; c < 64; ++c) {
            float wv = r3_w[c * 20 + tid];
            a0 += h2[0][c] * wv; a1 += h2[1][c] * wv;
            a2 += h2[2][c] * wv; a3 += h2[3][c] * wv;
        }
        float bb = r3_b[tid];
        logits[0][tid] = a0 + bb; logits[1][tid] = a1 + bb;
        logits[2][tid] = a2 + bb; logits[3][tid] = a3 + bb;
    }
    __syncthreads();
    if (tid < 4) {
        float m = -INFINITY;
        for (int u = 0; u < 20; ++u) m = fmaxf(m, logits[tid][u]);
        float s = 0.f;
        for (int u = 0; u < 20; ++u) s += expf(logits[tid][u] - m);
        lse[tid] = m + logf(s);
    }
    __syncthreads();
    if (tid < 80) {
        int rr = tid / 20, cls = tid % 20;
        out[(size_t)(bn0 + rr) * 20 + cls] = logits[rr][cls] - lse[rr];
    }
}

// ----------------------------------------------------------------------------
// Layout (ws >= NEED_A = 16,846,848 B — proven: Path A ran in round 10):
//   [0,4M)       f1T (phases 1-3) -> f2 bf16 (phase 3+)
//   [4M,+64K)    sqb | [4M+64K,8M+64K) f1 | [8M+64K,+640K) knn | +192K xT3
//   [4M,8M)      kkA (after ec2; f1/sqb dead) | [8M,12M) vtA
//   [12M,16M)    G (gemmG scratch, phases 1-3) -> atth (attention phase)
//   [16M,+68K)   pmax | glob
extern "C" void kernel_launch(void* const* d_in, const int* in_sizes, int n_in,
                              void* d_out, int out_size, void* d_ws, size_t ws_size,
                              hipStream_t stream) {
    const float* x      = (const float*)d_in[0];
    const float* ec1_w1 = (const float*)d_in[2];
    const float* ec1_b1 = (const float*)d_in[3];
    const float* ec1_w2 = (const float*)d_in[4];
    const float* ec1_b2 = (const float*)d_in[5];
    const float* ec2_w1 = (const float*)d_in[6];
    const float* ec2_b1 = (const float*)d_in[7];
    const float* ec2_w2 = (const float*)d_in[8];
    const float* ec2_b2 = (const float*)d_in[9];
    const float* qkv_w  = (const float*)d_in[10];
    const float* out_w  = (const float*)d_in[11];
    const float* out_b  = (const float*)d_in[12];
    const float* r1_w   = (const float*)d_in[13];
    const float* r1_b   = (const float*)d_in[14];
    const float* r2_w   = (const float*)d_in[15];
    const float* r2_b   = (const float*)d_in[16];
    const float* r3_w   = (const float*)d_in[17];
    const float* r3_b   = (const float*)d_in[18];
    float* out = (float*)d_out;

    const size_t MB = 1024 * 1024;
    const size_t NEED_A = 16 * MB + 65536 + 4096;
    if (ws_size < NEED_A) return;   // guard (clean numeric fail, not a fault)

    char* base = (char*)d_ws;
    bf16*  f2   = (bf16*)(base);
    float* f1T  = (float*)(base);
    float* sqb  = (float*)(base + 4 * MB);
    float* f1   = (float*)(base + 4 * MB + 65536);
    u16*   knn  = (u16*)(base + 8 * MB + 65536);
    float* xT3  = (float*)(base + 8 * MB + 65536 + 655360);
    float* G    = (float*)(base + 12 * MB);           // phases 1-3
    bf16*  kkA  = (bf16*)(base + 4 * MB);             // attention phase
    bf16*  vtA  = (bf16*)(base + 8 * MB);
    bf16*  atth = (bf16*)(base + 12 * MB);
    float* pmax = (float*)(base + 16 * MB);
    float* glob = (float*)(base + 16 * MB + 65536);

    sqT_kernel<3><<<BBNN / 256, 256, 0, stream>>>(x, sqb, xT3);
    knn_fast_kernel<3, 3><<<BB * 128, 512, 0, stream>>>(x, xT3, sqb, knn);
    gemmG_kernel<3><<<BBNN / 4, 256, 0, stream>>>(x, ec1_w1, G);
    edgeconv3_kernel<3, 64, false><<<BBNN / 4, 256, 0, stream>>>(
        x, knn, ec1_w1, ec1_b1, ec1_w2, ec1_b2, G, f1);

    sqT_kernel<64><<<BBNN / 256, 256, 0, stream>>>(f1, sqb, f1T);
    knn_fast_kernel<64, 8><<<BB * 128, 512, 0, stream>>>(f1, f1T, sqb, knn);
    gemmG_kernel<64><<<BBNN / 4, 256, 0, stream>>>(f1, ec2_w1, G);
    edgeconv3_kernel<64, 128, true><<<BBNN / 4, 256, 0, stream>>>(
        f1, knn, ec2_w1, ec2_b1, ec2_w2, ec2_b2, G, f2);

    gmax1_kernel<<<BB * 16, 128, 0, stream>>>(f2, pmax);
    gmax2_kernel<<<BB, 128, 0, stream>>>(pmax, glob);

    kvt_kernel<<<4 * BBNN / 4, 256, 0, stream>>>(f2, qkv_w, kkA, vtA);
    attn_mfma_kernel<<<BB * 4 * 32, 256, 0, stream>>>(f2, qkv_w, kkA, vtA, atth);

    final_kernel<<<BBNN / 4, 128, 0, stream>>>(
        f2, glob, atth, out_w, out_b, r1_w, r1_b, r2_w, r2_b, r3_w, r3_b, out);
}